// Round 3
// baseline (167.973 us; speedup 1.0000x reference)
//
#include <hip/hip_runtime.h>

// B=8, S=1024, H=128, rel rows R=129. All inputs/outputs are float32.
constexpr int Bn = 8, Sn = 1024, Hn = 128, Rn = 129, RLD = 132;
constexpr float INV_SCALE = 0.088388347648318447f; // 1/sqrt(128)
constexpr size_t YEL = (size_t)Bn * Sn * Hn;       // y output elements

typedef short bf16x8 __attribute__((ext_vector_type(8)));
typedef short v4s __attribute__((ext_vector_type(4)));
typedef float f32x4 __attribute__((ext_vector_type(4)));
typedef int v4i __attribute__((ext_vector_type(4)));

__device__ __forceinline__ float bf2f(short s) {
    unsigned u = ((unsigned)(unsigned short)s) << 16;
    float f; __builtin_memcpy(&f, &u, 4); return f;
}
__device__ __forceinline__ short f2bf(float f) {
    unsigned u; __builtin_memcpy(&u, &f, 4);
    unsigned r = (u + 0x7fffu + ((u >> 16) & 1u)) >> 16;
    return (short)(r & 0xffffu);
}

// Merged table builder:
//   blocks [0, Rn):        relcat[p] = [rh(128) | rh(128) | rl(128)]
//   blocks [Rn, Rn+107):   BcatT[n][k] (ld 320): k<128 -> Wo[k][n];
//                          128<=k<257 -> (rel_v@Wo)[k-128][n]; else 0
__global__ __launch_bounds__(384) void build_tables(
    const float* __restrict__ rel_k, const float* __restrict__ rel_v,
    const float* __restrict__ Wo,
    short* __restrict__ relcat, short* __restrict__ BcatT)
{
    if (blockIdx.x < Rn) {
        const int p = blockIdx.x, c = threadIdx.x;
        const int j = (c < 256) ? (c & 127) : (c - 256);
        float v = rel_k[p * Hn + j];
        short h = f2bf(v);
        relcat[p * 384 + c] = (c < 256) ? h : f2bf(v - bf2f(h));
    } else {
        int idx = (blockIdx.x - Rn) * 384 + threadIdx.x;   // 0..40959 (320x128)
        if (idx < 320 * 128) {
            int k = idx >> 7, n = idx & 127;
            float v;
            if (k < 128) v = Wo[k * Hn + n];
            else if (k < 257) {
                int p = k - 128; float a = 0.f;
                for (int h = 0; h < Hn; ++h) a += rel_v[p * Hn + h] * Wo[h * Hn + n];
                v = a;
            } else v = 0.f;
            BcatT[n * 320 + k] = f2bf(v);
        }
    }
}

// Fused fp32 VALU projections: y-dim selects Q (hi/lo qcat + qh), K (kh), V (vT).
__global__ __launch_bounds__(256) void proj(
    const float* __restrict__ X,
    const float* __restrict__ Wq, const float* __restrict__ bq,
    const float* __restrict__ Wk, const float* __restrict__ bk,
    const float* __restrict__ Wv, const float* __restrict__ bv,
    short* __restrict__ qh, short* __restrict__ qcat,
    short* __restrict__ kh, short* __restrict__ vT)
{
    __shared__ float xs[64][128];
    __shared__ float wsm[32][128];
    const int tid = threadIdx.x;
    const int sel = blockIdx.y;
    const int row0 = blockIdx.x * 64;
    const float* W = (sel == 0) ? Wq : (sel == 1) ? Wk : Wv;
    const float* bias = (sel == 0) ? bq : (sel == 1) ? bk : bv;

#pragma unroll
    for (int it = 0; it < 8; ++it) {
        int u = tid + it * 256;
        int r = u >> 5, c4 = (u & 31) * 4;
        *(float4*)&xs[r][c4] = *(const float4*)(X + (size_t)(row0 + r) * 128 + c4);
    }

    const int rg = tid >> 5, cg = tid & 31;
    float acc[8][4] = {};
    for (int kc = 0; kc < 128; kc += 32) {
#pragma unroll
        for (int it = 0; it < 4; ++it) {
            int u = tid + it * 256;
            int kk = u >> 5, c4 = (u & 31) * 4;
            *(float4*)&wsm[kk][c4] = *(const float4*)(W + (size_t)(kc + kk) * 128 + c4);
        }
        __syncthreads();
#pragma unroll 8
        for (int kk = 0; kk < 32; ++kk) {
            float wv[4];
#pragma unroll
            for (int c = 0; c < 4; ++c) wv[c] = wsm[kk][cg + c * 32];
#pragma unroll
            for (int r = 0; r < 8; ++r) {
                float xv = xs[rg * 8 + r][kc + kk];
#pragma unroll
                for (int c = 0; c < 4; ++c) acc[r][c] += xv * wv[c];
            }
        }
        __syncthreads();
    }

#pragma unroll
    for (int c = 0; c < 4; ++c) {
        int col = cg + c * 32;
        float bv2 = bias[col];
#pragma unroll
        for (int r = 0; r < 8; ++r) {
            int row = row0 + rg * 8 + r;
            float v = acc[r][c] + bv2;
            short h = f2bf(v);
            if (sel == 0) {
                qh[(size_t)row * 128 + col] = h;
                qcat[(size_t)row * 256 + col] = h;
                qcat[(size_t)row * 256 + 128 + col] = f2bf(v - bf2f(h));
            } else if (sel == 1) {
                kh[(size_t)row * 128 + col] = h;
            } else {
                int b = row >> 10, i = row & (Sn - 1);
                vT[(size_t)b * 131072 + (size_t)col * 1024 + i] = h;
            }
        }
    }
}

// qrel = [qh|ql|qh] @ [rh|rh|rl]^T  (K=384, f32-faithful q), 64x64 tiles.
// Staged (round-0 known-good version).
__global__ __launch_bounds__(256) void qrel_gemm(
    const short* __restrict__ qcat, const short* __restrict__ relcat,
    float* __restrict__ qrel)
{
    __shared__ short As[64][72];
    __shared__ short Bs[64][72];
    const int tid = threadIdx.x;
    const int wave = tid >> 6, lane = tid & 63;
    const int quad = lane >> 4, l15 = lane & 15;
    const int row0 = blockIdx.x * 64, col0 = blockIdx.y * 64;

    f32x4 acc[4] = {};
    for (int kc = 0; kc < 384; kc += 64) {
#pragma unroll
        for (int it = 0; it < 2; ++it) {
            int u = tid + it * 256;
            int r = u >> 3, c8 = (u & 7) * 8;
            int srcc = kc + c8;
            if (srcc >= 256) srcc -= 256;
            *(v4i*)&As[r][c8] = *(const v4i*)(qcat + (size_t)(row0 + r) * 256 + srcc);
        }
#pragma unroll
        for (int it = 0; it < 2; ++it) {
            int u = tid + it * 256;
            int r = u >> 3, c8 = (u & 7) * 8;
            v4i val = {0, 0, 0, 0};
            if (col0 + r < Rn)
                val = *(const v4i*)(relcat + (size_t)(col0 + r) * 384 + kc + c8);
            *(v4i*)&Bs[r][c8] = val;
        }
        __syncthreads();
#pragma unroll
        for (int ks = 0; ks < 64; ks += 32) {
            bf16x8 af = *(const bf16x8*)&As[wave * 16 + l15][ks + quad * 8];
#pragma unroll
            for (int nt = 0; nt < 4; ++nt) {
                bf16x8 bf = *(const bf16x8*)&Bs[nt * 16 + l15][ks + quad * 8];
                acc[nt] = __builtin_amdgcn_mfma_f32_16x16x32_bf16(af, bf, acc[nt], 0, 0, 0);
            }
        }
        __syncthreads();
    }
    const int rloc0 = wave * 16 + quad * 4;
#pragma unroll
    for (int nt = 0; nt < 4; ++nt) {
        int col = col0 + nt * 16 + l15;
#pragma unroll
        for (int r = 0; r < 4; ++r) {
            if (col < Rn)
                qrel[(size_t)(row0 + rloc0 + r) * RLD + col] = acc[nt][r];
        }
    }
}

// Fully fused: scores + softmax + attn-write + P@V + [ctx|arel]@BcatT
// + residual + LayerNorm -> y.
// v4: direct-global MFMA B-frags (round-1 numerics, which passed) + explicit
// 1-deep register prefetch (bnxt loaded for kt+1 while MFMAs consume bcur of
// kt; serial bcur=bnxt chain pins the pipeline depth). No LDS staging of
// kh/vT -> no staging barriers at all in phases 1/3 (7 syncthreads total,
// all around Pb/CtxA/LN). Compiler emits counted vmcnt(N) for the register
// loads automatically — no inline asm, no WAR hazards.
// kh/vT per batch are 256 KB each; XCD batch-affinity swizzle (batch =
// linear_block % 8) keeps each batch's K/V hot in one XCD's 4 MiB L2.
// LDS 46,080 B; __launch_bounds__(512,4) caps VGPR at 128 so 2 blocks/CU
// (4 waves/SIMD) stay resident for TLP on top of the prefetch ILP.
__global__ __launch_bounds__(512, 4) void fused_attn(
    const short* __restrict__ qh, const short* __restrict__ kh,
    const short* __restrict__ vT, const float* __restrict__ qrel_g,
    const short* __restrict__ BcatT,
    const float* __restrict__ X, const float* __restrict__ bo,
    const float* __restrict__ gamma, const float* __restrict__ beta,
    float* __restrict__ attn_g, float* __restrict__ y_g)
{
    __shared__ __align__(16) char smem[46080];
    short* Pb   = (short*)smem;               // [16][1032] bf16 P      (33,024 B)
    short* CtxA = (short*)(smem + 33024);     // [16][344]  [ctx|arel]  (11,008 B)
    float* QrL  = (float*)(smem + 33024);     // [16][132] overlays CtxA (dead before it)
    float* redM = (float*)(smem + 44032);     // 4x [16][8] reduction arrays
    float* redS = redM + 128;
    float* redL = redS + 128;
    float* redH = redL + 128;

    const int tid = threadIdx.x;
    const int w = tid >> 6, lane = tid & 63;
    const int quad = lane >> 4, l15 = lane & 15;
    // XCD batch-affinity swizzle (bijective: 512 % 8 == 0).
    const int lb = blockIdx.x + (blockIdx.z << 6);   // 0..511
    const int bz = lb & 7;
    const int row0 = (lb >> 3) << 4;
    const size_t grow0 = (size_t)bz * Sn + row0;

    const short* khb  = kh + (size_t)bz * Sn * 128;
    const short* vtb0 = vT + (size_t)bz * 131072;

    // stage qrel strip into QrL (wave w: rows 2w, 2w+1)
#pragma unroll
    for (int rr = 0; rr < 2; ++rr) {
        int r = w * 2 + rr;
        const float* src = qrel_g + (grow0 + r) * RLD;
        QrL[r * 132 + lane] = src[lane];
        QrL[r * 132 + 64 + lane] = src[64 + lane];
        if (lane < 4) QrL[r * 132 + 128 + lane] = src[128 + lane];
    }

    // A-frags: qh strip rows (one-time per-lane loads)
    bf16x8 afr[4];
#pragma unroll
    for (int kk = 0; kk < 4; ++kk)
        afr[kk] = *(const bf16x8*)(qh + (grow0 + l15) * 128 + kk * 32 + quad * 8);

    // ---- phase 1: scores; B-frags direct from kh (L2), 1-deep prefetch
    const short* krow = khb + (size_t)(w * 16 + l15) * 128 + quad * 8;
    f32x4 acc[8] = {};
    {
        bf16x8 bcur[4], bnxt[4];
#pragma unroll
        for (int kk = 0; kk < 4; ++kk)
            bcur[kk] = *(const bf16x8*)(krow + kk * 32);
#pragma unroll
        for (int kt = 0; kt < 8; ++kt) {
            if (kt < 7) {
#pragma unroll
                for (int kk = 0; kk < 4; ++kk)
                    bnxt[kk] = *(const bf16x8*)(krow + (size_t)(kt + 1) * 128 * 128 + kk * 32);
            }
#pragma unroll
            for (int kk = 0; kk < 4; ++kk)
                acc[kt] = __builtin_amdgcn_mfma_f32_16x16x32_bf16(afr[kk], bcur[kk], acc[kt], 0, 0, 0);
            if (kt < 7) {
#pragma unroll
                for (int kk = 0; kk < 4; ++kk) bcur[kk] = bnxt[kk];
            }
        }
    }
    __syncthreads();   // QrL staged (written at kernel start) now visible

    // ---- scale + qrel + row-max
    float mx[4];
#pragma unroll
    for (int r = 0; r < 4; ++r) {
        int lr = quad * 4 + r, i = row0 + lr;
        float m = -3.4e38f;
#pragma unroll
        for (int kt = 0; kt < 8; ++kt) {
            int col = kt * 128 + w * 16 + l15;
            int d = col - i; d = (d < -64) ? -64 : (d > 64 ? 64 : d);
            float v = acc[kt][r] * INV_SCALE + QrL[lr * 132 + d + 64];
            acc[kt][r] = v;
            m = fmaxf(m, v);
        }
#pragma unroll
        for (int msk = 1; msk < 16; msk <<= 1) m = fmaxf(m, __shfl_xor(m, msk));
        if (l15 == 0) redM[lr * 8 + w] = m;
    }
    __syncthreads();
#pragma unroll
    for (int r = 0; r < 4; ++r) {
        int lr = quad * 4 + r;
        float m = redM[lr * 8];
#pragma unroll
        for (int j = 1; j < 8; ++j) m = fmaxf(m, redM[lr * 8 + j]);
        mx[r] = m;
    }

    // ---- exp + partial sums (s, lo, hi)
#pragma unroll
    for (int r = 0; r < 4; ++r) {
        int lr = quad * 4 + r, i = row0 + lr;
        float s = 0.f, lo = 0.f, hi = 0.f;
#pragma unroll
        for (int kt = 0; kt < 8; ++kt) {
            float e = __expf(acc[kt][r] - mx[r]);
            acc[kt][r] = e;
            s += e;
            int col = kt * 128 + w * 16 + l15;
            lo += (col <= i - 64) ? e : 0.f;
            hi += (col >= i + 64) ? e : 0.f;
        }
#pragma unroll
        for (int msk = 1; msk < 16; msk <<= 1) {
            s += __shfl_xor(s, msk);
            lo += __shfl_xor(lo, msk);
            hi += __shfl_xor(hi, msk);
        }
        if (l15 == 0) { redS[lr * 8 + w] = s; redL[lr * 8 + w] = lo; redH[lr * 8 + w] = hi; }
    }
    __syncthreads();

    // ---- normalize into Pb (bf16)
#pragma unroll
    for (int r = 0; r < 4; ++r) {
        int lr = quad * 4 + r;
        float s = 0.f;
#pragma unroll
        for (int j = 0; j < 8; ++j) s += redS[lr * 8 + j];
        float inv = 1.0f / s;
#pragma unroll
        for (int kt = 0; kt < 8; ++kt) {
            int col = kt * 128 + w * 16 + l15;
            Pb[lr * 1032 + col] = f2bf(acc[kt][r] * inv);
        }
    }
    __syncthreads();   // Pb complete (and all QrL/score reads done)

    // ---- attn f32 output, fully coalesced float4 stores from Pb
    {
        float* ab = attn_g + grow0 * Sn;
#pragma unroll
        for (int it = 0; it < 8; ++it) {
            int u = tid + it * 512;            // 16 rows x 256 float4
            int r = u >> 8, c4 = (u & 255) * 4;
            v4s pv = *(const v4s*)&Pb[r * 1032 + c4];
            float4 o;
            o.x = bf2f(pv[0]); o.y = bf2f(pv[1]);
            o.z = bf2f(pv[2]); o.w = bf2f(pv[3]);
            *(float4*)(ab + (size_t)r * Sn + c4) = o;
        }
    }

    // ---- phase 3: ctx = P @ V; B-frags direct from vT (L2), 1-deep prefetch
    const short* vrow = vtb0 + (size_t)(w * 16 + l15) * 1024 + quad * 8;
    f32x4 cacc = {};
    {
        bf16x8 bcur[4], bnxt[4];
#pragma unroll
        for (int kk = 0; kk < 4; ++kk)
            bcur[kk] = *(const bf16x8*)(vrow + kk * 32);
#pragma unroll
        for (int kc = 0; kc < 8; ++kc) {
            if (kc < 7) {
#pragma unroll
                for (int kk = 0; kk < 4; ++kk)
                    bnxt[kk] = *(const bf16x8*)(vrow + (kc + 1) * 128 + kk * 32);
            }
#pragma unroll
            for (int kk = 0; kk < 4; ++kk) {
                bf16x8 a = *(const bf16x8*)&Pb[l15 * 1032 + kc * 128 + kk * 32 + quad * 8];
                cacc = __builtin_amdgcn_mfma_f32_16x16x32_bf16(a, bcur[kk], cacc, 0, 0, 0);
            }
            if (kc < 7) {
#pragma unroll
                for (int kk = 0; kk < 4; ++kk) bcur[kk] = bnxt[kk];
            }
        }
    }

    // ---- build CtxA = [bf16(ctx) | arel(129) | 0] in LDS (overlays dead QrL)
#pragma unroll
    for (int r = 0; r < 4; ++r)
        CtxA[(quad * 4 + r) * 344 + w * 16 + l15] = f2bf(cacc[r]);
#pragma unroll
    for (int rr = 0; rr < 2; ++rr) {
        int lr = w * 2 + rr, i = row0 + lr;
        float s = 0.f, lo = 0.f, hi = 0.f;
#pragma unroll
        for (int j = 0; j < 8; ++j) {
            s += redS[lr * 8 + j]; lo += redL[lr * 8 + j]; hi += redH[lr * 8 + j];
        }
        float inv = 1.0f / s;
        float v0;
        if (lane == 0) v0 = lo * inv;
        else { int c = i + lane - 64; v0 = (c >= 0 && c < Sn) ? bf2f(Pb[lr * 1032 + c]) : 0.f; }
        CtxA[lr * 344 + 128 + lane] = f2bf(v0);
        int c1 = i + lane;
        CtxA[lr * 344 + 192 + lane] = (c1 < Sn) ? Pb[lr * 1032 + c1] : (short)0;
        CtxA[lr * 344 + 256 + lane] = (lane == 0) ? f2bf(hi * inv) : (short)0;
    }
    __syncthreads();

    // ---- phase 4: y = LN([ctx|arel] @ BcatT^T + bo + x), B direct from BcatT (L2-hot)
    f32x4 yacc = {};
    const short* bcb = BcatT + (size_t)(w * 16 + l15) * 320;
#pragma unroll
    for (int ch = 0; ch < 3; ++ch) {
        const int nkk = (ch == 2) ? 2 : 4;
#pragma unroll
        for (int kk = 0; kk < 4; ++kk) {
            if (kk >= nkk) break;
            bf16x8 a = *(const bf16x8*)&CtxA[l15 * 344 + ch * 128 + kk * 32 + quad * 8];
            bf16x8 b = *(const bf16x8*)(bcb + ch * 128 + kk * 32 + quad * 8);
            yacc = __builtin_amdgcn_mfma_f32_16x16x32_bf16(a, b, yacc, 0, 0, 0);
        }
    }

    // ---- residual + LayerNorm epilogue
    const int col = w * 16 + l15;
    const float bov = bo[col], gv = gamma[col], bev = beta[col];
    float vv[4];
#pragma unroll
    for (int r = 0; r < 4; ++r) {
        int lr = quad * 4 + r;
        vv[r] = yacc[r] + bov + X[(grow0 + lr) * 128 + col];
    }
#pragma unroll
    for (int r = 0; r < 4; ++r) {
        float s = vv[r];
#pragma unroll
        for (int msk = 1; msk < 16; msk <<= 1) s += __shfl_xor(s, msk);
        if (l15 == 0) redM[(quad * 4 + r) * 8 + w] = s;
    }
    __syncthreads();
    float mu[4];
#pragma unroll
    for (int r = 0; r < 4; ++r) {
        int lr = quad * 4 + r;
        float s = 0.f;
#pragma unroll
        for (int j = 0; j < 8; ++j) s += redM[lr * 8 + j];
        mu[r] = s * (1.f / 128.f);
    }
#pragma unroll
    for (int r = 0; r < 4; ++r) {
        float d = vv[r] - mu[r];
        float s = d * d;
#pragma unroll
        for (int msk = 1; msk < 16; msk <<= 1) s += __shfl_xor(s, msk);
        if (l15 == 0) redS[(quad * 4 + r) * 8 + w] = s;
    }
    __syncthreads();
#pragma unroll
    for (int r = 0; r < 4; ++r) {
        int lr = quad * 4 + r;
        float s = 0.f;
#pragma unroll
        for (int j = 0; j < 8; ++j) s += redS[lr * 8 + j];
        float inv = rsqrtf(s * (1.f / 128.f) + 1e-5f);
        y_g[(grow0 + lr) * 128 + col] = (vv[r] - mu[r]) * inv * gv + bev;
    }
}

extern "C" void kernel_launch(void* const* d_in, const int* in_sizes, int n_in,
                              void* d_out, int out_size, void* d_ws, size_t ws_size,
                              hipStream_t stream) {
    const float* x     = (const float*)d_in[0];
    const float* Wq    = (const float*)d_in[1];
    const float* bq    = (const float*)d_in[2];
    const float* Wk    = (const float*)d_in[3];
    const float* bk    = (const float*)d_in[4];
    const float* Wv    = (const float*)d_in[5];
    const float* bv    = (const float*)d_in[6];
    const float* rel_k = (const float*)d_in[7];
    const float* rel_v = (const float*)d_in[8];
    const float* Wo    = (const float*)d_in[9];
    const float* bo    = (const float*)d_in[10];
    const float* gamma = (const float*)d_in[11];
    const float* beta  = (const float*)d_in[12];

    char* ws = (char*)d_ws;
    short* qh     = (short*)(ws + 0);          // 8192x128 bf16
    short* kh     = (short*)(ws + 2097152);
    short* vT     = (short*)(ws + 4194304);    // 8x128x1024 bf16
    short* qcat   = (short*)(ws + 6291456);    // 8192x256 bf16 hi|lo
    float* qrel   = (float*)(ws + 10485760);   // 8192x132 f32
    short* relcat = (short*)(ws + 14811136);   // 129x384 bf16 (99,072 B)
    short* BcatT  = (short*)(ws + 14910464);   // 128x320 bf16 — own slot

    float* y_out = (float*)d_out;
    float* attn  = (float*)d_out + YEL;        // 8x1024x1024 f32

    build_tables<<<dim3(Rn + 107), 384, 0, stream>>>(rel_k, rel_v, Wo, relcat, BcatT);
    proj<<<dim3(128, 3), 256, 0, stream>>>(x, Wq, bq, Wk, bk, Wv, bv, qh, qcat, kh, vT);
    qrel_gemm<<<dim3(128, 3), 256, 0, stream>>>(qcat, relcat, qrel);

    fused_attn<<<dim3(64, 1, Bn), 512, 0, stream>>>(
        qh, kh, vT, qrel, BcatT, x, bo, gamma, beta, attn, y_out);
}

// Round 6
// 157.776 us; speedup vs baseline: 1.0646x; 1.0646x over previous
//
#include <hip/hip_runtime.h>

// B=8, S=1024, H=128, rel rows R=129. All inputs/outputs are float32.
constexpr int Bn = 8, Sn = 1024, Hn = 128, Rn = 129, RLD = 132;
constexpr float INV_SCALE = 0.088388347648318447f; // 1/sqrt(128)
constexpr size_t YEL = (size_t)Bn * Sn * Hn;       // y output elements

typedef short bf16x8 __attribute__((ext_vector_type(8)));
typedef short v4s __attribute__((ext_vector_type(4)));
typedef float f32x4 __attribute__((ext_vector_type(4)));
typedef int v4i __attribute__((ext_vector_type(4)));

__device__ __forceinline__ float bf2f(short s) {
    unsigned u = ((unsigned)(unsigned short)s) << 16;
    float f; __builtin_memcpy(&f, &u, 4); return f;
}
__device__ __forceinline__ short f2bf(float f) {
    unsigned u; __builtin_memcpy(&u, &f, 4);
    unsigned r = (u + 0x7fffu + ((u >> 16) & 1u)) >> 16;
    return (short)(r & 0xffffu);
}

// Async 16B global -> LDS (direct-to-LDS DMA; dest = wave-uniform base + lane*16).
__device__ __forceinline__ void gll16(const short* g, short* l) {
    __builtin_amdgcn_global_load_lds(
        (const __attribute__((address_space(1))) void*)g,
        (__attribute__((address_space(3))) void*)l, 16, 0, 0);
}

// Merged table builder:
//   blocks [0, Rn):        relcat[p] = [rh(128) | rh(128) | rl(128)]
//   blocks [Rn, Rn+107):   BcatT[n][k] (ld 320): k<128 -> Wo[k][n];
//                          128<=k<257 -> (rel_v@Wo)[k-128][n]; else 0
__global__ __launch_bounds__(384) void build_tables(
    const float* __restrict__ rel_k, const float* __restrict__ rel_v,
    const float* __restrict__ Wo,
    short* __restrict__ relcat, short* __restrict__ BcatT)
{
    if (blockIdx.x < Rn) {
        const int p = blockIdx.x, c = threadIdx.x;
        const int j = (c < 256) ? (c & 127) : (c - 256);
        float v = rel_k[p * Hn + j];
        short h = f2bf(v);
        relcat[p * 384 + c] = (c < 256) ? h : f2bf(v - bf2f(h));
    } else {
        int idx = (blockIdx.x - Rn) * 384 + threadIdx.x;   // 0..40959 (320x128)
        if (idx < 320 * 128) {
            int k = idx >> 7, n = idx & 127;
            float v;
            if (k < 128) v = Wo[k * Hn + n];
            else if (k < 257) {
                int p = k - 128; float a = 0.f;
                for (int h = 0; h < Hn; ++h) a += rel_v[p * Hn + h] * Wo[h * Hn + n];
                v = a;
            } else v = 0.f;
            BcatT[n * 320 + k] = f2bf(v);
        }
    }
}

// Fused fp32 VALU projections: y-dim selects Q (hi/lo qcat + qh), K (kh), V (vT).
__global__ __launch_bounds__(256) void proj(
    const float* __restrict__ X,
    const float* __restrict__ Wq, const float* __restrict__ bq,
    const float* __restrict__ Wk, const float* __restrict__ bk,
    const float* __restrict__ Wv, const float* __restrict__ bv,
    short* __restrict__ qh, short* __restrict__ qcat,
    short* __restrict__ kh, short* __restrict__ vT)
{
    __shared__ float xs[64][128];
    __shared__ float wsm[32][128];
    const int tid = threadIdx.x;
    const int sel = blockIdx.y;
    const int row0 = blockIdx.x * 64;
    const float* W = (sel == 0) ? Wq : (sel == 1) ? Wk : Wv;
    const float* bias = (sel == 0) ? bq : (sel == 1) ? bk : bv;

#pragma unroll
    for (int it = 0; it < 8; ++it) {
        int u = tid + it * 256;
        int r = u >> 5, c4 = (u & 31) * 4;
        *(float4*)&xs[r][c4] = *(const float4*)(X + (size_t)(row0 + r) * 128 + c4);
    }

    const int rg = tid >> 5, cg = tid & 31;
    float acc[8][4] = {};
    for (int kc = 0; kc < 128; kc += 32) {
#pragma unroll
        for (int it = 0; it < 4; ++it) {
            int u = tid + it * 256;
            int kk = u >> 5, c4 = (u & 31) * 4;
            *(float4*)&wsm[kk][c4] = *(const float4*)(W + (size_t)(kc + kk) * 128 + c4);
        }
        __syncthreads();
#pragma unroll 8
        for (int kk = 0; kk < 32; ++kk) {
            float wv[4];
#pragma unroll
            for (int c = 0; c < 4; ++c) wv[c] = wsm[kk][cg + c * 32];
#pragma unroll
            for (int r = 0; r < 8; ++r) {
                float xv = xs[rg * 8 + r][kc + kk];
#pragma unroll
                for (int c = 0; c < 4; ++c) acc[r][c] += xv * wv[c];
            }
        }
        __syncthreads();
    }

#pragma unroll
    for (int c = 0; c < 4; ++c) {
        int col = cg + c * 32;
        float bv2 = bias[col];
#pragma unroll
        for (int r = 0; r < 8; ++r) {
            int row = row0 + rg * 8 + r;
            float v = acc[r][c] + bv2;
            short h = f2bf(v);
            if (sel == 0) {
                qh[(size_t)row * 128 + col] = h;
                qcat[(size_t)row * 256 + col] = h;
                qcat[(size_t)row * 256 + 128 + col] = f2bf(v - bf2f(h));
            } else if (sel == 1) {
                kh[(size_t)row * 128 + col] = h;
            } else {
                int b = row >> 10, i = row & (Sn - 1);
                vT[(size_t)b * 131072 + (size_t)col * 1024 + i] = h;
            }
        }
    }
}

// qrel = [qh|ql|qh] @ [rh|rh|rl]^T  (K=384, f32-faithful q), 64x64 tiles.
// Staged (round-0 known-good version).
__global__ __launch_bounds__(256) void qrel_gemm(
    const short* __restrict__ qcat, const short* __restrict__ relcat,
    float* __restrict__ qrel)
{
    __shared__ short As[64][72];
    __shared__ short Bs[64][72];
    const int tid = threadIdx.x;
    const int wave = tid >> 6, lane = tid & 63;
    const int quad = lane >> 4, l15 = lane & 15;
    const int row0 = blockIdx.x * 64, col0 = blockIdx.y * 64;

    f32x4 acc[4] = {};
    for (int kc = 0; kc < 384; kc += 64) {
#pragma unroll
        for (int it = 0; it < 2; ++it) {
            int u = tid + it * 256;
            int r = u >> 3, c8 = (u & 7) * 8;
            int srcc = kc + c8;
            if (srcc >= 256) srcc -= 256;
            *(v4i*)&As[r][c8] = *(const v4i*)(qcat + (size_t)(row0 + r) * 256 + srcc);
        }
#pragma unroll
        for (int it = 0; it < 2; ++it) {
            int u = tid + it * 256;
            int r = u >> 3, c8 = (u & 7) * 8;
            v4i val = {0, 0, 0, 0};
            if (col0 + r < Rn)
                val = *(const v4i*)(relcat + (size_t)(col0 + r) * 384 + kc + c8);
            *(v4i*)&Bs[r][c8] = val;
        }
        __syncthreads();
#pragma unroll
        for (int ks = 0; ks < 64; ks += 32) {
            bf16x8 af = *(const bf16x8*)&As[wave * 16 + l15][ks + quad * 8];
#pragma unroll
            for (int nt = 0; nt < 4; ++nt) {
                bf16x8 bf = *(const bf16x8*)&Bs[nt * 16 + l15][ks + quad * 8];
                acc[nt] = __builtin_amdgcn_mfma_f32_16x16x32_bf16(af, bf, acc[nt], 0, 0, 0);
            }
        }
        __syncthreads();
    }
    const int rloc0 = wave * 16 + quad * 4;
#pragma unroll
    for (int nt = 0; nt < 4; ++nt) {
        int col = col0 + nt * 16 + l15;
#pragma unroll
        for (int r = 0; r < 4; ++r) {
            if (col < Rn)
                qrel[(size_t)(row0 + rloc0 + r) * RLD + col] = acc[nt][r];
        }
    }
}

// Fully fused: scores + softmax + attn-write + P@V + [ctx|arel]@BcatT
// + residual + LayerNorm -> y.
// v5 = round-2 structure (async gll16 dbuf staging) + ONE change:
// NON-TEMPORAL output stores (attn + y). Theory: the 37.7 MB attn/y write
// stream was write-allocating through the per-XCD L2s (4.7 MB/XCD vs 4 MiB
// capacity), thrashing K/V and draining at ~1 TB/s — the floor every
// variant hit. NT stores bypass L2 allocation -> K/V stays resident, write
// stream goes out at streaming rate (fills prove ~5.9 TB/s available).
// (v5b: NT store must use a native ext_vector type, not HIP float4 class.)
__global__ __launch_bounds__(512, 4) void fused_attn(
    const short* __restrict__ qh, const short* __restrict__ kh,
    const short* __restrict__ vT, const float* __restrict__ qrel_g,
    const short* __restrict__ BcatT,
    const float* __restrict__ X, const float* __restrict__ bo,
    const float* __restrict__ gamma, const float* __restrict__ beta,
    float* __restrict__ attn_g, float* __restrict__ y_g)
{
    __shared__ __align__(16) char smem[78848];
    short* bufS = (short*)smem;               // 32,768 B: 2 x 16,384 halves
    short* Pb   = (short*)(smem + 32768);     // [16][1032] bf16 P      (33,024 B)
    short* CtxA = (short*)(smem + 65792);     // [16][344]  [ctx|arel]  (11,008 B)
    float* QrL  = (float*)(smem + 65792);     // [16][132] overlays CtxA (dead before it)
    float* redM = (float*)(smem + 76800);     // 4x [16][8] reduction arrays
    float* redS = redM + 128;
    float* redL = redS + 128;
    float* redH = redL + 128;

    const int tid = threadIdx.x;
    const int w = tid >> 6, lane = tid & 63;
    const int quad = lane >> 4, l15 = lane & 15;
    // XCD batch-affinity swizzle (bijective: 512 % 8 == 0).
    const int lb = blockIdx.x + (blockIdx.z << 6);   // 0..511
    const int bz = lb & 7;
    const int row0 = (lb >> 3) << 4;
    const size_t grow0 = (size_t)bz * Sn + row0;

    const short* khb  = kh + (size_t)bz * Sn * 128;
    const short* vtb0 = vT + (size_t)bz * 131072;

    // stage qrel strip into QrL (wave w: rows 2w, 2w+1)
#pragma unroll
    for (int rr = 0; rr < 2; ++rr) {
        int r = w * 2 + rr;
        const float* src = qrel_g + (grow0 + r) * RLD;
        QrL[r * 132 + lane] = src[lane];
        QrL[r * 132 + 64 + lane] = src[64 + lane];
        if (lane < 4) QrL[r * 132 + 128 + lane] = src[128 + lane];
    }

    // A-frags: qh strip rows (one-time per-lane loads)
    bf16x8 afr[4];
#pragma unroll
    for (int kk = 0; kk < 4; ++kk)
        afr[kk] = *(const bf16x8*)(qh + (grow0 + l15) * 128 + kk * 32 + quad * 8);

    // Staging lambdas: half-tile = 128 rows x 64 shorts (16 KB), 2 x 16B/thread.
    // LDS linear at g*16B; source chunk XOR-swizzled: c ^= (r&7).
    auto stage_kh = [&](int kt2) {
        const short* base = khb + (size_t)((kt2 >> 1) * 128) * 128 + (kt2 & 1) * 64;
        short* dst = bufS + (kt2 & 1) * 8192;
#pragma unroll
        for (int it = 0; it < 2; ++it) {
            int g = tid + it * 512;
            int r = g >> 3, c = g & 7;
            gll16(base + r * 128 + ((c ^ (r & 7)) * 8), dst + g * 8);
        }
    };
    auto stage_v = [&](int kc2) {
        const short* base = vtb0 + (kc2 >> 1) * 128 + (kc2 & 1) * 64;
        short* dst = bufS + (kc2 & 1) * 8192;
#pragma unroll
        for (int it = 0; it < 2; ++it) {
            int g = tid + it * 512;
            int r = g >> 3, c = g & 7;
            gll16(base + r * 1024 + ((c ^ (r & 7)) * 8), dst + g * 8);
        }
    };

    // ---- phase 1: scores, 16 dbuf'd half-tile rounds
    stage_kh(0);
    __syncthreads();
    f32x4 acc[8] = {};
#pragma unroll
    for (int kt2 = 0; kt2 < 16; ++kt2) {
        if (kt2 < 15) stage_kh(kt2 + 1);     // issue BEFORE compute (T3-min)
        const short* hb = bufS + (kt2 & 1) * 8192;
        const int rb = w * 16 + l15;
#pragma unroll
        for (int kk = 0; kk < 2; ++kk) {
            int j = (kk * 4 + quad) ^ (l15 & 7);
            bf16x8 b = *(const bf16x8*)(hb + rb * 64 + j * 8);
            acc[kt2 >> 1] = __builtin_amdgcn_mfma_f32_16x16x32_bf16(
                afr[(kt2 & 1) * 2 + kk], b, acc[kt2 >> 1], 0, 0, 0);
        }
        __syncthreads();   // drains stage(kt2+1); protects next overwrite
    }

    // issue first vT half now — drained by softmax's own barriers
    stage_v(0);

    // ---- scale + qrel + row-max
    float mx[4];
#pragma unroll
    for (int r = 0; r < 4; ++r) {
        int lr = quad * 4 + r, i = row0 + lr;
        float m = -3.4e38f;
#pragma unroll
        for (int kt = 0; kt < 8; ++kt) {
            int col = kt * 128 + w * 16 + l15;
            int d = col - i; d = (d < -64) ? -64 : (d > 64 ? 64 : d);
            float v = acc[kt][r] * INV_SCALE + QrL[lr * 132 + d + 64];
            acc[kt][r] = v;
            m = fmaxf(m, v);
        }
#pragma unroll
        for (int msk = 1; msk < 16; msk <<= 1) m = fmaxf(m, __shfl_xor(m, msk));
        if (l15 == 0) redM[lr * 8 + w] = m;
    }
    __syncthreads();
#pragma unroll
    for (int r = 0; r < 4; ++r) {
        int lr = quad * 4 + r;
        float m = redM[lr * 8];
#pragma unroll
        for (int j = 1; j < 8; ++j) m = fmaxf(m, redM[lr * 8 + j]);
        mx[r] = m;
    }

    // ---- exp + partial sums (s, lo, hi)
#pragma unroll
    for (int r = 0; r < 4; ++r) {
        int lr = quad * 4 + r, i = row0 + lr;
        float s = 0.f, lo = 0.f, hi = 0.f;
#pragma unroll
        for (int kt = 0; kt < 8; ++kt) {
            float e = __expf(acc[kt][r] - mx[r]);
            acc[kt][r] = e;
            s += e;
            int col = kt * 128 + w * 16 + l15;
            lo += (col <= i - 64) ? e : 0.f;
            hi += (col >= i + 64) ? e : 0.f;
        }
#pragma unroll
        for (int msk = 1; msk < 16; msk <<= 1) {
            s += __shfl_xor(s, msk);
            lo += __shfl_xor(lo, msk);
            hi += __shfl_xor(hi, msk);
        }
        if (l15 == 0) { redS[lr * 8 + w] = s; redL[lr * 8 + w] = lo; redH[lr * 8 + w] = hi; }
    }
    __syncthreads();

    // ---- normalize into Pb (bf16)
#pragma unroll
    for (int r = 0; r < 4; ++r) {
        int lr = quad * 4 + r;
        float s = 0.f;
#pragma unroll
        for (int j = 0; j < 8; ++j) s += redS[lr * 8 + j];
        float inv = 1.0f / s;
#pragma unroll
        for (int kt = 0; kt < 8; ++kt) {
            int col = kt * 128 + w * 16 + l15;
            Pb[lr * 1032 + col] = f2bf(acc[kt][r] * inv);
        }
    }
    __syncthreads();   // Pb complete; stage_v(0) also drained by now

    // ---- attn f32 output: coalesced NON-TEMPORAL f32x4 stores from Pb
    {
        float* ab = attn_g + grow0 * Sn;
#pragma unroll
        for (int it = 0; it < 8; ++it) {
            int u = tid + it * 512;            // 16 rows x 256 float4
            int r = u >> 8, c4 = (u & 255) * 4;
            v4s pv = *(const v4s*)&Pb[r * 1032 + c4];
            f32x4 o;
            o[0] = bf2f(pv[0]); o[1] = bf2f(pv[1]);
            o[2] = bf2f(pv[2]); o[3] = bf2f(pv[3]);
            __builtin_nontemporal_store(o, (f32x4*)(ab + (size_t)r * Sn + c4));
        }
    }

    // ---- phase 3: ctx = P @ V, 16 dbuf'd vT half-tile rounds
    f32x4 cacc = {};
#pragma unroll
    for (int kc2 = 0; kc2 < 16; ++kc2) {
        if (kc2 < 15) stage_v(kc2 + 1);
        const short* hb = bufS + (kc2 & 1) * 8192;
        const int rb = w * 16 + l15;
#pragma unroll
        for (int kk = 0; kk < 2; ++kk) {
            bf16x8 a = *(const bf16x8*)&Pb[l15 * 1032 + kc2 * 64 + kk * 32 + quad * 8];
            int j = (kk * 4 + quad) ^ (l15 & 7);
            bf16x8 b = *(const bf16x8*)(hb + rb * 64 + j * 8);
            cacc = __builtin_amdgcn_mfma_f32_16x16x32_bf16(a, b, cacc, 0, 0, 0);
        }
        __syncthreads();
    }

    // ---- build CtxA = [bf16(ctx) | arel(129) | 0] in LDS (overlays dead QrL)
#pragma unroll
    for (int r = 0; r < 4; ++r)
        CtxA[(quad * 4 + r) * 344 + w * 16 + l15] = f2bf(cacc[r]);
#pragma unroll
    for (int rr = 0; rr < 2; ++rr) {
        int lr = w * 2 + rr, i = row0 + lr;
        float s = 0.f, lo = 0.f, hi = 0.f;
#pragma unroll
        for (int j = 0; j < 8; ++j) {
            s += redS[lr * 8 + j]; lo += redL[lr * 8 + j]; hi += redH[lr * 8 + j];
        }
        float inv = 1.0f / s;
        float v0;
        if (lane == 0) v0 = lo * inv;
        else { int c = i + lane - 64; v0 = (c >= 0 && c < Sn) ? bf2f(Pb[lr * 1032 + c]) : 0.f; }
        CtxA[lr * 344 + 128 + lane] = f2bf(v0);
        int c1 = i + lane;
        CtxA[lr * 344 + 192 + lane] = (c1 < Sn) ? Pb[lr * 1032 + c1] : (short)0;
        CtxA[lr * 344 + 256 + lane] = (lane == 0) ? f2bf(hi * inv) : (short)0;
    }
    __syncthreads();

    // ---- phase 4: y = LN([ctx|arel] @ BcatT^T + bo + x), B direct from BcatT (L2-hot)
    f32x4 yacc = {};
    const short* bcb = BcatT + (size_t)(w * 16 + l15) * 320;
#pragma unroll
    for (int ch = 0; ch < 3; ++ch) {
        const int nkk = (ch == 2) ? 2 : 4;
#pragma unroll
        for (int kk = 0; kk < 4; ++kk) {
            if (kk >= nkk) break;
            bf16x8 a = *(const bf16x8*)&CtxA[l15 * 344 + ch * 128 + kk * 32 + quad * 8];
            bf16x8 b = *(const bf16x8*)(bcb + ch * 128 + kk * 32 + quad * 8);
            yacc = __builtin_amdgcn_mfma_f32_16x16x32_bf16(a, b, yacc, 0, 0, 0);
        }
    }

    // ---- residual + LayerNorm epilogue
    const int col = w * 16 + l15;
    const float bov = bo[col], gv = gamma[col], bev = beta[col];
    float vv[4];
#pragma unroll
    for (int r = 0; r < 4; ++r) {
        int lr = quad * 4 + r;
        vv[r] = yacc[r] + bov + X[(grow0 + lr) * 128 + col];
    }
#pragma unroll
    for (int r = 0; r < 4; ++r) {
        float s = vv[r];
#pragma unroll
        for (int msk = 1; msk < 16; msk <<= 1) s += __shfl_xor(s, msk);
        if (l15 == 0) redM[(quad * 4 + r) * 8 + w] = s;
    }
    __syncthreads();
    float mu[4];
#pragma unroll
    for (int r = 0; r < 4; ++r) {
        int lr = quad * 4 + r;
        float s = 0.f;
#pragma unroll
        for (int j = 0; j < 8; ++j) s += redM[lr * 8 + j];
        mu[r] = s * (1.f / 128.f);
    }
#pragma unroll
    for (int r = 0; r < 4; ++r) {
        float d = vv[r] - mu[r];
        float s = d * d;
#pragma unroll
        for (int msk = 1; msk < 16; msk <<= 1) s += __shfl_xor(s, msk);
        if (l15 == 0) redS[(quad * 4 + r) * 8 + w] = s;
    }
    __syncthreads();
#pragma unroll
    for (int r = 0; r < 4; ++r) {
        int lr = quad * 4 + r;
        float s = 0.f;
#pragma unroll
        for (int j = 0; j < 8; ++j) s += redS[lr * 8 + j];
        float inv = rsqrtf(s * (1.f / 128.f) + 1e-5f);
        float yv = (vv[r] - mu[r]) * inv * gv + bev;
        __builtin_nontemporal_store(yv, &y_g[(grow0 + lr) * 128 + col]);
    }
}

extern "C" void kernel_launch(void* const* d_in, const int* in_sizes, int n_in,
                              void* d_out, int out_size, void* d_ws, size_t ws_size,
                              hipStream_t stream) {
    const float* x     = (const float*)d_in[0];
    const float* Wq    = (const float*)d_in[1];
    const float* bq    = (const float*)d_in[2];
    const float* Wk    = (const float*)d_in[3];
    const float* bk    = (const float*)d_in[4];
    const float* Wv    = (const float*)d_in[5];
    const float* bv    = (const float*)d_in[6];
    const float* rel_k = (const float*)d_in[7];
    const float* rel_v = (const float*)d_in[8];
    const float* Wo    = (const float*)d_in[9];
    const float* bo    = (const float*)d_in[10];
    const float* gamma = (const float*)d_in[11];
    const float* beta  = (const float*)d_in[12];

    char* ws = (char*)d_ws;
    short* qh     = (short*)(ws + 0);          // 8192x128 bf16
    short* kh     = (short*)(ws + 2097152);
    short* vT     = (short*)(ws + 4194304);    // 8x128x1024 bf16
    short* qcat   = (short*)(ws + 6291456);    // 8192x256 bf16 hi|lo
    float* qrel   = (float*)(ws + 10485760);   // 8192x132 f32
    short* relcat = (short*)(ws + 14811136);   // 129x384 bf16 (99,072 B)
    short* BcatT  = (short*)(ws + 14910464);   // 128x320 bf16 — own slot

    float* y_out = (float*)d_out;
    float* attn  = (float*)d_out + YEL;        // 8x1024x1024 f32

    build_tables<<<dim3(Rn + 107), 384, 0, stream>>>(rel_k, rel_v, Wo, relcat, BcatT);
    proj<<<dim3(128, 3), 256, 0, stream>>>(x, Wq, bq, Wk, bk, Wv, bv, qh, qcat, kh, vT);
    qrel_gemm<<<dim3(128, 3), 256, 0, stream>>>(qcat, relcat, qrel);

    fused_attn<<<dim3(64, 1, Bn), 512, 0, stream>>>(
        qh, kh, vT, qrel, BcatT, x, bo, gamma, beta, attn, y_out);
}

// Round 7
// 155.784 us; speedup vs baseline: 1.0782x; 1.0128x over previous
//
#include <hip/hip_runtime.h>

// B=8, S=1024, H=128, rel rows R=129. All inputs/outputs are float32.
constexpr int Bn = 8, Sn = 1024, Hn = 128, Rn = 129;
constexpr float INV_SCALE = 0.088388347648318447f; // 1/sqrt(128)
constexpr size_t YEL = (size_t)Bn * Sn * Hn;       // y output elements

typedef short bf16x8 __attribute__((ext_vector_type(8)));
typedef short v4s __attribute__((ext_vector_type(4)));
typedef float f32x4 __attribute__((ext_vector_type(4)));
typedef int v4i __attribute__((ext_vector_type(4)));

__device__ __forceinline__ float bf2f(short s) {
    unsigned u = ((unsigned)(unsigned short)s) << 16;
    float f; __builtin_memcpy(&f, &u, 4); return f;
}
__device__ __forceinline__ short f2bf(float f) {
    unsigned u; __builtin_memcpy(&u, &f, 4);
    unsigned r = (u + 0x7fffu + ((u >> 16) & 1u)) >> 16;
    return (short)(r & 0xffffu);
}

// Async 16B global -> LDS (direct-to-LDS DMA; dest = wave-uniform base + lane*16).
__device__ __forceinline__ void gll16(const short* g, short* l) {
    __builtin_amdgcn_global_load_lds(
        (const __attribute__((address_space(1))) void*)g,
        (__attribute__((address_space(3))) void*)l, 16, 0, 0);
}

// Merged table builder:
//   blocks [0, Rn):        relcat[p] = [rh(128) | rh(128) | rl(128)]
//   blocks [Rn, Rn+107):   BcatT[n][k] (ld 320): k<128 -> Wo[k][n];
//                          128<=k<257 -> (rel_v@Wo)[k-128][n]; else 0
__global__ __launch_bounds__(384) void build_tables(
    const float* __restrict__ rel_k, const float* __restrict__ rel_v,
    const float* __restrict__ Wo,
    short* __restrict__ relcat, short* __restrict__ BcatT)
{
    if (blockIdx.x < Rn) {
        const int p = blockIdx.x, c = threadIdx.x;
        const int j = (c < 256) ? (c & 127) : (c - 256);
        float v = rel_k[p * Hn + j];
        short h = f2bf(v);
        relcat[p * 384 + c] = (c < 256) ? h : f2bf(v - bf2f(h));
    } else {
        int idx = (blockIdx.x - Rn) * 384 + threadIdx.x;   // 0..40959 (320x128)
        if (idx < 320 * 128) {
            int k = idx >> 7, n = idx & 127;
            float v;
            if (k < 128) v = Wo[k * Hn + n];
            else if (k < 257) {
                int p = k - 128; float a = 0.f;
                for (int h = 0; h < Hn; ++h) a += rel_v[p * Hn + h] * Wo[h * Hn + n];
                v = a;
            } else v = 0.f;
            BcatT[n * 320 + k] = f2bf(v);
        }
    }
}

// Fused fp32 VALU projections: y-dim selects Q (hi/lo qcat), K (kh), V (vT).
__global__ __launch_bounds__(256) void proj(
    const float* __restrict__ X,
    const float* __restrict__ Wq, const float* __restrict__ bq,
    const float* __restrict__ Wk, const float* __restrict__ bk,
    const float* __restrict__ Wv, const float* __restrict__ bv,
    short* __restrict__ qcat, short* __restrict__ kh, short* __restrict__ vT)
{
    __shared__ float xs[64][128];
    __shared__ float wsm[32][128];
    const int tid = threadIdx.x;
    const int sel = blockIdx.y;
    const int row0 = blockIdx.x * 64;
    const float* W = (sel == 0) ? Wq : (sel == 1) ? Wk : Wv;
    const float* bias = (sel == 0) ? bq : (sel == 1) ? bk : bv;

#pragma unroll
    for (int it = 0; it < 8; ++it) {
        int u = tid + it * 256;
        int r = u >> 5, c4 = (u & 31) * 4;
        *(float4*)&xs[r][c4] = *(const float4*)(X + (size_t)(row0 + r) * 128 + c4);
    }

    const int rg = tid >> 5, cg = tid & 31;
    float acc[8][4] = {};
    for (int kc = 0; kc < 128; kc += 32) {
#pragma unroll
        for (int it = 0; it < 4; ++it) {
            int u = tid + it * 256;
            int kk = u >> 5, c4 = (u & 31) * 4;
            *(float4*)&wsm[kk][c4] = *(const float4*)(W + (size_t)(kc + kk) * 128 + c4);
        }
        __syncthreads();
#pragma unroll 8
        for (int kk = 0; kk < 32; ++kk) {
            float wv[4];
#pragma unroll
            for (int c = 0; c < 4; ++c) wv[c] = wsm[kk][cg + c * 32];
#pragma unroll
            for (int r = 0; r < 8; ++r) {
                float xv = xs[rg * 8 + r][kc + kk];
#pragma unroll
                for (int c = 0; c < 4; ++c) acc[r][c] += xv * wv[c];
            }
        }
        __syncthreads();
    }

#pragma unroll
    for (int c = 0; c < 4; ++c) {
        int col = cg + c * 32;
        float bv2 = bias[col];
#pragma unroll
        for (int r = 0; r < 8; ++r) {
            int row = row0 + rg * 8 + r;
            float v = acc[r][c] + bv2;
            short h = f2bf(v);
            if (sel == 0) {
                qcat[(size_t)row * 256 + col] = h;
                qcat[(size_t)row * 256 + 128 + col] = f2bf(v - bf2f(h));
            } else if (sel == 1) {
                kh[(size_t)row * 128 + col] = h;
            } else {
                int b = row >> 10, i = row & (Sn - 1);
                vT[(size_t)b * 131072 + (size_t)col * 1024 + i] = h;
            }
        }
    }
}

// Fully fused: qrel (merged!) + scores + softmax + attn-write + P@V +
// [ctx|arel]@BcatT + residual + LayerNorm -> y.
// v6 = r6 structure + qrel_gemm MERGED into a per-wave MFMA prologue:
// wave w computes qrel cols [w*16, w*16+16) (wave 0 also col 128) from
// qcat[16x256 strip] x relcat[129x384] directly into QrL — removes the
// qrel_gemm launch, its 4.3 MB write, and our 4.3 MB re-read. The prologue
// also hides stage_kh(0) latency behind real MFMA work. qh buffer dropped:
// phase-1 A-frags read qcat's hi half (same bytes).
// OOB relcat rows (p>128, from the nt=8 tile) read inside the padded 128 KB
// relcat slot and are masked on write (garbage B-cols only affect masked
// output cols — MFMA column independence).
__global__ __launch_bounds__(512, 4) void fused_attn(
    const short* __restrict__ qcat, const short* __restrict__ kh,
    const short* __restrict__ vT, const short* __restrict__ relcat,
    const short* __restrict__ BcatT,
    const float* __restrict__ X, const float* __restrict__ bo,
    const float* __restrict__ gamma, const float* __restrict__ beta,
    float* __restrict__ attn_g, float* __restrict__ y_g)
{
    __shared__ __align__(16) char smem[78848];
    short* bufS = (short*)smem;               // 32,768 B: 2 x 16,384 halves
    short* Pb   = (short*)(smem + 32768);     // [16][1032] bf16 P      (33,024 B)
    short* CtxA = (short*)(smem + 65792);     // [16][344]  [ctx|arel]  (11,008 B)
    float* QrL  = (float*)(smem + 65792);     // [16][132] overlays CtxA (dead before it)
    float* redM = (float*)(smem + 76800);     // 4x [16][8] reduction arrays
    float* redS = redM + 128;
    float* redL = redS + 128;
    float* redH = redL + 128;

    const int tid = threadIdx.x;
    const int w = tid >> 6, lane = tid & 63;
    const int quad = lane >> 4, l15 = lane & 15;
    // XCD batch-affinity swizzle (bijective: 512 % 8 == 0).
    const int lb = blockIdx.x + (blockIdx.z << 6);   // 0..511
    const int bz = lb & 7;
    const int row0 = (lb >> 3) << 4;
    const size_t grow0 = (size_t)bz * Sn + row0;

    const short* khb  = kh + (size_t)bz * Sn * 128;
    const short* vtb0 = vT + (size_t)bz * 131072;

    // Staging lambdas: half-tile = 128 rows x 64 shorts (16 KB), 2 x 16B/thread.
    // LDS linear at g*16B; source chunk XOR-swizzled: c ^= (r&7).
    auto stage_kh = [&](int kt2) {
        const short* base = khb + (size_t)((kt2 >> 1) * 128) * 128 + (kt2 & 1) * 64;
        short* dst = bufS + (kt2 & 1) * 8192;
#pragma unroll
        for (int it = 0; it < 2; ++it) {
            int g = tid + it * 512;
            int r = g >> 3, c = g & 7;
            gll16(base + r * 128 + ((c ^ (r & 7)) * 8), dst + g * 8);
        }
    };
    auto stage_v = [&](int kc2) {
        const short* base = vtb0 + (kc2 >> 1) * 128 + (kc2 & 1) * 64;
        short* dst = bufS + (kc2 & 1) * 8192;
#pragma unroll
        for (int it = 0; it < 2; ++it) {
            int g = tid + it * 512;
            int r = g >> 3, c = g & 7;
            gll16(base + r * 1024 + ((c ^ (r & 7)) * 8), dst + g * 8);
        }
    };

    // issue first kh half-tile now; the qrel prologue below hides its latency
    stage_kh(0);

    // A-frags: q strip rows from qcat hi half (one-time per-lane loads)
    bf16x8 afr[4];
#pragma unroll
    for (int kk = 0; kk < 4; ++kk)
        afr[kk] = *(const bf16x8*)(qcat + (grow0 + l15) * 256 + kk * 32 + quad * 8);

    // ---- merged qrel prologue: QrL[lr][p] = q_f32(lr) . rel_k(p)
    // K=384 over [qh|ql|qh] x [rh|rh|rl]; wave w owns cols p = w*16+l15,
    // wave 0 additionally p = 128+l15 (masked to p==128 on write).
    {
        const short* aq = qcat + (grow0 + l15) * 256;
        const short* br = relcat + (size_t)(w * 16 + l15) * 384;
        const short* br2 = relcat + (size_t)(128 + l15) * 384;  // wave 0 extra tile
        f32x4 qacc = {};
        f32x4 qacc2 = {};
#pragma unroll
        for (int ks = 0; ks < 12; ++ks) {
            int koff = ks * 32 + quad * 8;
            int srcc = (koff >= 256) ? koff - 256 : koff;
            bf16x8 qa = *(const bf16x8*)(aq + srcc);
            bf16x8 qb = *(const bf16x8*)(br + ks * 32 + quad * 8);
            qacc = __builtin_amdgcn_mfma_f32_16x16x32_bf16(qa, qb, qacc, 0, 0, 0);
            if (w == 0) {
                bf16x8 qb2 = *(const bf16x8*)(br2 + ks * 32 + quad * 8);
                qacc2 = __builtin_amdgcn_mfma_f32_16x16x32_bf16(qa, qb2, qacc2, 0, 0, 0);
            }
        }
#pragma unroll
        for (int r = 0; r < 4; ++r)
            QrL[(quad * 4 + r) * 132 + w * 16 + l15] = qacc[r];
        if (w == 0 && l15 == 0) {
#pragma unroll
            for (int r = 0; r < 4; ++r)
                QrL[(quad * 4 + r) * 132 + 128] = qacc2[r];
        }
    }
    __syncthreads();   // QrL complete; stage_kh(0) drained

    // ---- phase 1: scores, 16 dbuf'd half-tile rounds
    f32x4 acc[8] = {};
#pragma unroll
    for (int kt2 = 0; kt2 < 16; ++kt2) {
        if (kt2 < 15) stage_kh(kt2 + 1);     // issue BEFORE compute (T3-min)
        const short* hb = bufS + (kt2 & 1) * 8192;
        const int rb = w * 16 + l15;
#pragma unroll
        for (int kk = 0; kk < 2; ++kk) {
            int j = (kk * 4 + quad) ^ (l15 & 7);
            bf16x8 b = *(const bf16x8*)(hb + rb * 64 + j * 8);
            acc[kt2 >> 1] = __builtin_amdgcn_mfma_f32_16x16x32_bf16(
                afr[(kt2 & 1) * 2 + kk], b, acc[kt2 >> 1], 0, 0, 0);
        }
        __syncthreads();   // drains stage(kt2+1); protects next overwrite
    }

    // issue first vT half now — drained by softmax's own barriers
    stage_v(0);

    // ---- scale + qrel + row-max
    float mx[4];
#pragma unroll
    for (int r = 0; r < 4; ++r) {
        int lr = quad * 4 + r, i = row0 + lr;
        float m = -3.4e38f;
#pragma unroll
        for (int kt = 0; kt < 8; ++kt) {
            int col = kt * 128 + w * 16 + l15;
            int d = col - i; d = (d < -64) ? -64 : (d > 64 ? 64 : d);
            float v = acc[kt][r] * INV_SCALE + QrL[lr * 132 + d + 64];
            acc[kt][r] = v;
            m = fmaxf(m, v);
        }
#pragma unroll
        for (int msk = 1; msk < 16; msk <<= 1) m = fmaxf(m, __shfl_xor(m, msk));
        if (l15 == 0) redM[lr * 8 + w] = m;
    }
    __syncthreads();
#pragma unroll
    for (int r = 0; r < 4; ++r) {
        int lr = quad * 4 + r;
        float m = redM[lr * 8];
#pragma unroll
        for (int j = 1; j < 8; ++j) m = fmaxf(m, redM[lr * 8 + j]);
        mx[r] = m;
    }

    // ---- exp + partial sums (s, lo, hi)
#pragma unroll
    for (int r = 0; r < 4; ++r) {
        int lr = quad * 4 + r, i = row0 + lr;
        float s = 0.f, lo = 0.f, hi = 0.f;
#pragma unroll
        for (int kt = 0; kt < 8; ++kt) {
            float e = __expf(acc[kt][r] - mx[r]);
            acc[kt][r] = e;
            s += e;
            int col = kt * 128 + w * 16 + l15;
            lo += (col <= i - 64) ? e : 0.f;
            hi += (col >= i + 64) ? e : 0.f;
        }
#pragma unroll
        for (int msk = 1; msk < 16; msk <<= 1) {
            s += __shfl_xor(s, msk);
            lo += __shfl_xor(lo, msk);
            hi += __shfl_xor(hi, msk);
        }
        if (l15 == 0) { redS[lr * 8 + w] = s; redL[lr * 8 + w] = lo; redH[lr * 8 + w] = hi; }
    }
    __syncthreads();

    // ---- normalize into Pb (bf16)
#pragma unroll
    for (int r = 0; r < 4; ++r) {
        int lr = quad * 4 + r;
        float s = 0.f;
#pragma unroll
        for (int j = 0; j < 8; ++j) s += redS[lr * 8 + j];
        float inv = 1.0f / s;
#pragma unroll
        for (int kt = 0; kt < 8; ++kt) {
            int col = kt * 128 + w * 16 + l15;
            Pb[lr * 1032 + col] = f2bf(acc[kt][r] * inv);
        }
    }
    __syncthreads();   // Pb complete; stage_v(0) also drained by now

    // ---- attn f32 output: coalesced NON-TEMPORAL f32x4 stores from Pb
    {
        float* ab = attn_g + grow0 * Sn;
#pragma unroll
        for (int it = 0; it < 8; ++it) {
            int u = tid + it * 512;            // 16 rows x 256 float4
            int r = u >> 8, c4 = (u & 255) * 4;
            v4s pv = *(const v4s*)&Pb[r * 1032 + c4];
            f32x4 o;
            o[0] = bf2f(pv[0]); o[1] = bf2f(pv[1]);
            o[2] = bf2f(pv[2]); o[3] = bf2f(pv[3]);
            __builtin_nontemporal_store(o, (f32x4*)(ab + (size_t)r * Sn + c4));
        }
    }

    // ---- phase 3: ctx = P @ V, 16 dbuf'd vT half-tile rounds
    f32x4 cacc = {};
#pragma unroll
    for (int kc2 = 0; kc2 < 16; ++kc2) {
        if (kc2 < 15) stage_v(kc2 + 1);
        const short* hb = bufS + (kc2 & 1) * 8192;
        const int rb = w * 16 + l15;
#pragma unroll
        for (int kk = 0; kk < 2; ++kk) {
            bf16x8 a = *(const bf16x8*)&Pb[l15 * 1032 + kc2 * 64 + kk * 32 + quad * 8];
            int j = (kk * 4 + quad) ^ (l15 & 7);
            bf16x8 b = *(const bf16x8*)(hb + rb * 64 + j * 8);
            cacc = __builtin_amdgcn_mfma_f32_16x16x32_bf16(a, b, cacc, 0, 0, 0);
        }
        __syncthreads();
    }

    // ---- build CtxA = [bf16(ctx) | arel(129) | 0] in LDS (overlays dead QrL)
#pragma unroll
    for (int r = 0; r < 4; ++r)
        CtxA[(quad * 4 + r) * 344 + w * 16 + l15] = f2bf(cacc[r]);
#pragma unroll
    for (int rr = 0; rr < 2; ++rr) {
        int lr = w * 2 + rr, i = row0 + lr;
        float s = 0.f, lo = 0.f, hi = 0.f;
#pragma unroll
        for (int j = 0; j < 8; ++j) {
            s += redS[lr * 8 + j]; lo += redL[lr * 8 + j]; hi += redH[lr * 8 + j];
        }
        float inv = 1.0f / s;
        float v0;
        if (lane == 0) v0 = lo * inv;
        else { int c = i + lane - 64; v0 = (c >= 0 && c < Sn) ? bf2f(Pb[lr * 1032 + c]) : 0.f; }
        CtxA[lr * 344 + 128 + lane] = f2bf(v0);
        int c1 = i + lane;
        CtxA[lr * 344 + 192 + lane] = (c1 < Sn) ? Pb[lr * 1032 + c1] : (short)0;
        CtxA[lr * 344 + 256 + lane] = (lane == 0) ? f2bf(hi * inv) : (short)0;
    }
    __syncthreads();

    // ---- phase 4: y = LN([ctx|arel] @ BcatT^T + bo + x), B direct from BcatT (L2-hot)
    f32x4 yacc = {};
    const short* bcb = BcatT + (size_t)(w * 16 + l15) * 320;
#pragma unroll
    for (int ch = 0; ch < 3; ++ch) {
        const int nkk = (ch == 2) ? 2 : 4;
#pragma unroll
        for (int kk = 0; kk < 4; ++kk) {
            if (kk >= nkk) break;
            bf16x8 a = *(const bf16x8*)&CtxA[l15 * 344 + ch * 128 + kk * 32 + quad * 8];
            bf16x8 b = *(const bf16x8*)(bcb + ch * 128 + kk * 32 + quad * 8);
            yacc = __builtin_amdgcn_mfma_f32_16x16x32_bf16(a, b, yacc, 0, 0, 0);
        }
    }

    // ---- residual + LayerNorm epilogue
    const int col = w * 16 + l15;
    const float bov = bo[col], gv = gamma[col], bev = beta[col];
    float vv[4];
#pragma unroll
    for (int r = 0; r < 4; ++r) {
        int lr = quad * 4 + r;
        vv[r] = yacc[r] + bov + X[(grow0 + lr) * 128 + col];
    }
#pragma unroll
    for (int r = 0; r < 4; ++r) {
        float s = vv[r];
#pragma unroll
        for (int msk = 1; msk < 16; msk <<= 1) s += __shfl_xor(s, msk);
        if (l15 == 0) redM[(quad * 4 + r) * 8 + w] = s;
    }
    __syncthreads();
    float mu[4];
#pragma unroll
    for (int r = 0; r < 4; ++r) {
        int lr = quad * 4 + r;
        float s = 0.f;
#pragma unroll
        for (int j = 0; j < 8; ++j) s += redM[lr * 8 + j];
        mu[r] = s * (1.f / 128.f);
    }
#pragma unroll
    for (int r = 0; r < 4; ++r) {
        float d = vv[r] - mu[r];
        float s = d * d;
#pragma unroll
        for (int msk = 1; msk < 16; msk <<= 1) s += __shfl_xor(s, msk);
        if (l15 == 0) redS[(quad * 4 + r) * 8 + w] = s;
    }
    __syncthreads();
#pragma unroll
    for (int r = 0; r < 4; ++r) {
        int lr = quad * 4 + r;
        float s = 0.f;
#pragma unroll
        for (int j = 0; j < 8; ++j) s += redS[lr * 8 + j];
        float inv = rsqrtf(s * (1.f / 128.f) + 1e-5f);
        float yv = (vv[r] - mu[r]) * inv * gv + bev;
        __builtin_nontemporal_store(yv, &y_g[(grow0 + lr) * 128 + col]);
    }
}

extern "C" void kernel_launch(void* const* d_in, const int* in_sizes, int n_in,
                              void* d_out, int out_size, void* d_ws, size_t ws_size,
                              hipStream_t stream) {
    const float* x     = (const float*)d_in[0];
    const float* Wq    = (const float*)d_in[1];
    const float* bq    = (const float*)d_in[2];
    const float* Wk    = (const float*)d_in[3];
    const float* bk    = (const float*)d_in[4];
    const float* Wv    = (const float*)d_in[5];
    const float* bv    = (const float*)d_in[6];
    const float* rel_k = (const float*)d_in[7];
    const float* rel_v = (const float*)d_in[8];
    const float* Wo    = (const float*)d_in[9];
    const float* bo    = (const float*)d_in[10];
    const float* gamma = (const float*)d_in[11];
    const float* beta  = (const float*)d_in[12];

    char* ws = (char*)d_ws;
    short* kh     = (short*)(ws + 0);          // 8x1024x128 bf16 (2 MB)
    short* vT     = (short*)(ws + 2097152);    // 8x128x1024 bf16 (2 MB)
    short* qcat   = (short*)(ws + 4194304);    // 8192x256 bf16 hi|lo (4 MB)
    short* relcat = (short*)(ws + 8388608);    // 129x384 bf16 in a padded 128 KB slot
    short* BcatT  = (short*)(ws + 8519680);    // 128x320 bf16

    float* y_out = (float*)d_out;
    float* attn  = (float*)d_out + YEL;        // 8x1024x1024 f32

    build_tables<<<dim3(Rn + 107), 384, 0, stream>>>(rel_k, rel_v, Wo, relcat, BcatT);
    proj<<<dim3(128, 3), 256, 0, stream>>>(x, Wq, bq, Wk, bk, Wv, bv, qcat, kh, vT);

    fused_attn<<<dim3(64, 1, Bn), 512, 0, stream>>>(
        qcat, kh, vT, relcat, BcatT, x, bo, gamma, beta, attn, y_out);
}

// Round 8
// 155.784 us; speedup vs baseline: 1.0782x; 1.0000x over previous
//
#include <hip/hip_runtime.h>

// B=8, S=1024, H=128, rel rows R=129. All inputs/outputs are float32.
constexpr int Bn = 8, Sn = 1024, Hn = 128, Rn = 129;
constexpr float INV_SCALE = 0.088388347648318447f; // 1/sqrt(128)
constexpr size_t YEL = (size_t)Bn * Sn * Hn;       // y output elements

typedef short bf16x8 __attribute__((ext_vector_type(8)));
typedef short v4s __attribute__((ext_vector_type(4)));
typedef float f32x4 __attribute__((ext_vector_type(4)));
typedef int v4i __attribute__((ext_vector_type(4)));

__device__ __forceinline__ float bf2f(short s) {
    unsigned u = ((unsigned)(unsigned short)s) << 16;
    float f; __builtin_memcpy(&f, &u, 4); return f;
}
__device__ __forceinline__ short f2bf(float f) {
    unsigned u; __builtin_memcpy(&u, &f, 4);
    unsigned r = (u + 0x7fffu + ((u >> 16) & 1u)) >> 16;
    return (short)(r & 0xffffu);
}

// Async 16B global -> LDS (direct-to-LDS DMA; dest = wave-uniform base + lane*16).
__device__ __forceinline__ void gll16(const short* g, short* l) {
    __builtin_amdgcn_global_load_lds(
        (const __attribute__((address_space(1))) void*)g,
        (__attribute__((address_space(3))) void*)l, 16, 0, 0);
}

// Merged table builder:
//   blocks [0, Rn):            relcat[p] = [rh(128) | rh(128) | rl(128)]
//   blocks [Rn, Rn+107):       BcatT[n][k] (ld 320)
//   blocks [Rn+107, Rn+235):   wtab: transposed hi/lo bf16 weights for proj:
//                              wtab[sel][part][n*128+k] = part? lo : hi of W_sel[k][n]
__global__ __launch_bounds__(384) void build_tables(
    const float* __restrict__ rel_k, const float* __restrict__ rel_v,
    const float* __restrict__ Wo,
    const float* __restrict__ Wq, const float* __restrict__ Wk,
    const float* __restrict__ Wv,
    short* __restrict__ relcat, short* __restrict__ BcatT,
    short* __restrict__ wtab)
{
    if (blockIdx.x < Rn) {
        const int p = blockIdx.x, c = threadIdx.x;
        const int j = (c < 256) ? (c & 127) : (c - 256);
        float v = rel_k[p * Hn + j];
        short h = f2bf(v);
        relcat[p * 384 + c] = (c < 256) ? h : f2bf(v - bf2f(h));
    } else if (blockIdx.x < Rn + 107) {
        int idx = (blockIdx.x - Rn) * 384 + threadIdx.x;   // 0..40959 (320x128)
        if (idx < 320 * 128) {
            int k = idx >> 7, n = idx & 127;
            float v;
            if (k < 128) v = Wo[k * Hn + n];
            else if (k < 257) {
                int p = k - 128; float a = 0.f;
                for (int h = 0; h < Hn; ++h) a += rel_v[p * Hn + h] * Wo[h * Hn + n];
                v = a;
            } else v = 0.f;
            BcatT[n * 320 + k] = f2bf(v);
        }
    } else {
        // 128 blocks x 384 threads = 49152 = 3 x 128 x 128 (sel, n, k)
        int idx = (blockIdx.x - Rn - 107) * 384 + threadIdx.x;
        int sel = idx >> 14, rem = idx & 16383;
        int n = rem >> 7, k = rem & 127;
        const float* W = (sel == 0) ? Wq : (sel == 1) ? Wk : Wv;
        float v = W[k * Hn + n];
        short h = f2bf(v);
        wtab[sel * 32768 + n * 128 + k] = h;
        wtab[sel * 32768 + 16384 + n * 128 + k] = f2bf(v - bf2f(h));
    }
}

// MFMA projections (replaces fp32 VALU proj): q = xh@wh + xh@wl + xl@wh
// (xl@wl dropped: ~1.5e-4, far below kh's bf16 rounding). 64 rows x 128 cols
// per block, 4 waves; Xs staged f32 in LDS; WtT hi/lo read direct from the
// L2-resident wtab (32 KB x 2 per sel, reused by all 128 blocks of that sel).
__global__ __launch_bounds__(256) void proj(
    const float* __restrict__ X, const short* __restrict__ wtab,
    const float* __restrict__ bq, const float* __restrict__ bk,
    const float* __restrict__ bv,
    short* __restrict__ qcat, short* __restrict__ kh, short* __restrict__ vT)
{
    __shared__ float xs[64][128];
    const int tid = threadIdx.x;
    const int sel = blockIdx.y;
    const int row0 = blockIdx.x * 64;
    const float* bias = (sel == 0) ? bq : (sel == 1) ? bk : bv;
    const short* wh = wtab + sel * 32768;
    const short* wl = wh + 16384;

#pragma unroll
    for (int it = 0; it < 8; ++it) {
        int u = tid + it * 256;
        int r = u >> 5, c4 = (u & 31) * 4;
        *(float4*)&xs[r][c4] = *(const float4*)(X + (size_t)(row0 + r) * 128 + c4);
    }
    __syncthreads();

    const int w = tid >> 6, lane = tid & 63;
    const int quad = lane >> 4, l15 = lane & 15;

    // A-frags: x row (w*16 + l15), k = kk*32 + quad*8 .. +8, hi/lo bf16
    bf16x8 xh[4], xl[4];
#pragma unroll
    for (int kk = 0; kk < 4; ++kk) {
#pragma unroll
        for (int j = 0; j < 8; ++j) {
            float v = xs[w * 16 + l15][kk * 32 + quad * 8 + j];
            short h = f2bf(v);
            xh[kk][j] = h;
            xl[kk][j] = f2bf(v - bf2f(h));
        }
    }

    // 8 col-tiles x 4 k-chunks x 3 terms
    f32x4 acc[8] = {};
#pragma unroll
    for (int nt = 0; nt < 8; ++nt) {
        const short* bh = wh + (size_t)(nt * 16 + l15) * 128;
        const short* bl = wl + (size_t)(nt * 16 + l15) * 128;
#pragma unroll
        for (int kk = 0; kk < 4; ++kk) {
            bf16x8 bhf = *(const bf16x8*)(bh + kk * 32 + quad * 8);
            bf16x8 blf = *(const bf16x8*)(bl + kk * 32 + quad * 8);
            acc[nt] = __builtin_amdgcn_mfma_f32_16x16x32_bf16(xh[kk], bhf, acc[nt], 0, 0, 0);
            acc[nt] = __builtin_amdgcn_mfma_f32_16x16x32_bf16(xh[kk], blf, acc[nt], 0, 0, 0);
            acc[nt] = __builtin_amdgcn_mfma_f32_16x16x32_bf16(xl[kk], bhf, acc[nt], 0, 0, 0);
        }
    }

    // epilogue: C row = row0 + w*16 + quad*4 + r, col = nt*16 + l15
#pragma unroll
    for (int nt = 0; nt < 8; ++nt) {
        int col = nt * 16 + l15;
        float bv2 = bias[col];
#pragma unroll
        for (int r = 0; r < 4; ++r) {
            int row = row0 + w * 16 + quad * 4 + r;
            float v = acc[nt][r] + bv2;
            short h = f2bf(v);
            if (sel == 0) {
                qcat[(size_t)row * 256 + col] = h;
                qcat[(size_t)row * 256 + 128 + col] = f2bf(v - bf2f(h));
            } else if (sel == 1) {
                kh[(size_t)row * 128 + col] = h;
            } else {
                int b = row >> 10, i = row & (Sn - 1);
                vT[(size_t)b * 131072 + (size_t)col * 1024 + i] = h;
            }
        }
    }
}

// Fully fused: qrel (merged) + scores + softmax + attn-write + P@V +
// [ctx|arel]@BcatT + residual + LayerNorm -> y.  (Unchanged from round 7.)
__global__ __launch_bounds__(512, 4) void fused_attn(
    const short* __restrict__ qcat, const short* __restrict__ kh,
    const short* __restrict__ vT, const short* __restrict__ relcat,
    const short* __restrict__ BcatT,
    const float* __restrict__ X, const float* __restrict__ bo,
    const float* __restrict__ gamma, const float* __restrict__ beta,
    float* __restrict__ attn_g, float* __restrict__ y_g)
{
    __shared__ __align__(16) char smem[78848];
    short* bufS = (short*)smem;               // 32,768 B: 2 x 16,384 halves
    short* Pb   = (short*)(smem + 32768);     // [16][1032] bf16 P      (33,024 B)
    short* CtxA = (short*)(smem + 65792);     // [16][344]  [ctx|arel]  (11,008 B)
    float* QrL  = (float*)(smem + 65792);     // [16][132] overlays CtxA (dead before it)
    float* redM = (float*)(smem + 76800);     // 4x [16][8] reduction arrays
    float* redS = redM + 128;
    float* redL = redS + 128;
    float* redH = redL + 128;

    const int tid = threadIdx.x;
    const int w = tid >> 6, lane = tid & 63;
    const int quad = lane >> 4, l15 = lane & 15;
    // XCD batch-affinity swizzle (bijective: 512 % 8 == 0).
    const int lb = blockIdx.x + (blockIdx.z << 6);   // 0..511
    const int bz = lb & 7;
    const int row0 = (lb >> 3) << 4;
    const size_t grow0 = (size_t)bz * Sn + row0;

    const short* khb  = kh + (size_t)bz * Sn * 128;
    const short* vtb0 = vT + (size_t)bz * 131072;

    auto stage_kh = [&](int kt2) {
        const short* base = khb + (size_t)((kt2 >> 1) * 128) * 128 + (kt2 & 1) * 64;
        short* dst = bufS + (kt2 & 1) * 8192;
#pragma unroll
        for (int it = 0; it < 2; ++it) {
            int g = tid + it * 512;
            int r = g >> 3, c = g & 7;
            gll16(base + r * 128 + ((c ^ (r & 7)) * 8), dst + g * 8);
        }
    };
    auto stage_v = [&](int kc2) {
        const short* base = vtb0 + (kc2 >> 1) * 128 + (kc2 & 1) * 64;
        short* dst = bufS + (kc2 & 1) * 8192;
#pragma unroll
        for (int it = 0; it < 2; ++it) {
            int g = tid + it * 512;
            int r = g >> 3, c = g & 7;
            gll16(base + r * 1024 + ((c ^ (r & 7)) * 8), dst + g * 8);
        }
    };

    // issue first kh half-tile now; the qrel prologue below hides its latency
    stage_kh(0);

    // A-frags: q strip rows from qcat hi half (one-time per-lane loads)
    bf16x8 afr[4];
#pragma unroll
    for (int kk = 0; kk < 4; ++kk)
        afr[kk] = *(const bf16x8*)(qcat + (grow0 + l15) * 256 + kk * 32 + quad * 8);

    // ---- merged qrel prologue: QrL[lr][p] = q_f32(lr) . rel_k(p)
    {
        const short* aq = qcat + (grow0 + l15) * 256;
        const short* br = relcat + (size_t)(w * 16 + l15) * 384;
        const short* br2 = relcat + (size_t)(128 + l15) * 384;  // wave 0 extra tile
        f32x4 qacc = {};
        f32x4 qacc2 = {};
#pragma unroll
        for (int ks = 0; ks < 12; ++ks) {
            int koff = ks * 32 + quad * 8;
            int srcc = (koff >= 256) ? koff - 256 : koff;
            bf16x8 qa = *(const bf16x8*)(aq + srcc);
            bf16x8 qb = *(const bf16x8*)(br + ks * 32 + quad * 8);
            qacc = __builtin_amdgcn_mfma_f32_16x16x32_bf16(qa, qb, qacc, 0, 0, 0);
            if (w == 0) {
                bf16x8 qb2 = *(const bf16x8*)(br2 + ks * 32 + quad * 8);
                qacc2 = __builtin_amdgcn_mfma_f32_16x16x32_bf16(qa, qb2, qacc2, 0, 0, 0);
            }
        }
#pragma unroll
        for (int r = 0; r < 4; ++r)
            QrL[(quad * 4 + r) * 132 + w * 16 + l15] = qacc[r];
        if (w == 0 && l15 == 0) {
#pragma unroll
            for (int r = 0; r < 4; ++r)
                QrL[(quad * 4 + r) * 132 + 128] = qacc2[r];
        }
    }
    __syncthreads();   // QrL complete; stage_kh(0) drained

    // ---- phase 1: scores, 16 dbuf'd half-tile rounds
    f32x4 acc[8] = {};
#pragma unroll
    for (int kt2 = 0; kt2 < 16; ++kt2) {
        if (kt2 < 15) stage_kh(kt2 + 1);     // issue BEFORE compute (T3-min)
        const short* hb = bufS + (kt2 & 1) * 8192;
        const int rb = w * 16 + l15;
#pragma unroll
        for (int kk = 0; kk < 2; ++kk) {
            int j = (kk * 4 + quad) ^ (l15 & 7);
            bf16x8 b = *(const bf16x8*)(hb + rb * 64 + j * 8);
            acc[kt2 >> 1] = __builtin_amdgcn_mfma_f32_16x16x32_bf16(
                afr[(kt2 & 1) * 2 + kk], b, acc[kt2 >> 1], 0, 0, 0);
        }
        __syncthreads();   // drains stage(kt2+1); protects next overwrite
    }

    // issue first vT half now — drained by softmax's own barriers
    stage_v(0);

    // ---- scale + qrel + row-max
    float mx[4];
#pragma unroll
    for (int r = 0; r < 4; ++r) {
        int lr = quad * 4 + r, i = row0 + lr;
        float m = -3.4e38f;
#pragma unroll
        for (int kt = 0; kt < 8; ++kt) {
            int col = kt * 128 + w * 16 + l15;
            int d = col - i; d = (d < -64) ? -64 : (d > 64 ? 64 : d);
            float v = acc[kt][r] * INV_SCALE + QrL[lr * 132 + d + 64];
            acc[kt][r] = v;
            m = fmaxf(m, v);
        }
#pragma unroll
        for (int msk = 1; msk < 16; msk <<= 1) m = fmaxf(m, __shfl_xor(m, msk));
        if (l15 == 0) redM[lr * 8 + w] = m;
    }
    __syncthreads();
#pragma unroll
    for (int r = 0; r < 4; ++r) {
        int lr = quad * 4 + r;
        float m = redM[lr * 8];
#pragma unroll
        for (int j = 1; j < 8; ++j) m = fmaxf(m, redM[lr * 8 + j]);
        mx[r] = m;
    }

    // ---- exp + partial sums (s, lo, hi)
#pragma unroll
    for (int r = 0; r < 4; ++r) {
        int lr = quad * 4 + r, i = row0 + lr;
        float s = 0.f, lo = 0.f, hi = 0.f;
#pragma unroll
        for (int kt = 0; kt < 8; ++kt) {
            float e = __expf(acc[kt][r] - mx[r]);
            acc[kt][r] = e;
            s += e;
            int col = kt * 128 + w * 16 + l15;
            lo += (col <= i - 64) ? e : 0.f;
            hi += (col >= i + 64) ? e : 0.f;
        }
#pragma unroll
        for (int msk = 1; msk < 16; msk <<= 1) {
            s += __shfl_xor(s, msk);
            lo += __shfl_xor(lo, msk);
            hi += __shfl_xor(hi, msk);
        }
        if (l15 == 0) { redS[lr * 8 + w] = s; redL[lr * 8 + w] = lo; redH[lr * 8 + w] = hi; }
    }
    __syncthreads();

    // ---- normalize into Pb (bf16)
#pragma unroll
    for (int r = 0; r < 4; ++r) {
        int lr = quad * 4 + r;
        float s = 0.f;
#pragma unroll
        for (int j = 0; j < 8; ++j) s += redS[lr * 8 + j];
        float inv = 1.0f / s;
#pragma unroll
        for (int kt = 0; kt < 8; ++kt) {
            int col = kt * 128 + w * 16 + l15;
            Pb[lr * 1032 + col] = f2bf(acc[kt][r] * inv);
        }
    }
    __syncthreads();   // Pb complete; stage_v(0) also drained by now

    // ---- attn f32 output: coalesced NON-TEMPORAL f32x4 stores from Pb
    {
        float* ab = attn_g + grow0 * Sn;
#pragma unroll
        for (int it = 0; it < 8; ++it) {
            int u = tid + it * 512;            // 16 rows x 256 float4
            int r = u >> 8, c4 = (u & 255) * 4;
            v4s pv = *(const v4s*)&Pb[r * 1032 + c4];
            f32x4 o;
            o[0] = bf2f(pv[0]); o[1] = bf2f(pv[1]);
            o[2] = bf2f(pv[2]); o[3] = bf2f(pv[3]);
            __builtin_nontemporal_store(o, (f32x4*)(ab + (size_t)r * Sn + c4));
        }
    }

    // ---- phase 3: ctx = P @ V, 16 dbuf'd vT half-tile rounds
    f32x4 cacc = {};
#pragma unroll
    for (int kc2 = 0; kc2 < 16; ++kc2) {
        if (kc2 < 15) stage_v(kc2 + 1);
        const short* hb = bufS + (kc2 & 1) * 8192;
        const int rb = w * 16 + l15;
#pragma unroll
        for (int kk = 0; kk < 2; ++kk) {
            bf16x8 a = *(const bf16x8*)&Pb[l15 * 1032 + kc2 * 64 + kk * 32 + quad * 8];
            int j = (kk * 4 + quad) ^ (l15 & 7);
            bf16x8 b = *(const bf16x8*)(hb + rb * 64 + j * 8);
            cacc = __builtin_amdgcn_mfma_f32_16x16x32_bf16(a, b, cacc, 0, 0, 0);
        }
        __syncthreads();
    }

    // ---- build CtxA = [bf16(ctx) | arel(129) | 0] in LDS (overlays dead QrL)
#pragma unroll
    for (int r = 0; r < 4; ++r)
        CtxA[(quad * 4 + r) * 344 + w * 16 + l15] = f2bf(cacc[r]);
#pragma unroll
    for (int rr = 0; rr < 2; ++rr) {
        int lr = w * 2 + rr, i = row0 + lr;
        float s = 0.f, lo = 0.f, hi = 0.f;
#pragma unroll
        for (int j = 0; j < 8; ++j) {
            s += redS[lr * 8 + j]; lo += redL[lr * 8 + j]; hi += redH[lr * 8 + j];
        }
        float inv = 1.0f / s;
        float v0;
        if (lane == 0) v0 = lo * inv;
        else { int c = i + lane - 64; v0 = (c >= 0 && c < Sn) ? bf2f(Pb[lr * 1032 + c]) : 0.f; }
        CtxA[lr * 344 + 128 + lane] = f2bf(v0);
        int c1 = i + lane;
        CtxA[lr * 344 + 192 + lane] = (c1 < Sn) ? Pb[lr * 1032 + c1] : (short)0;
        CtxA[lr * 344 + 256 + lane] = (lane == 0) ? f2bf(hi * inv) : (short)0;
    }
    __syncthreads();

    // ---- phase 4: y = LN([ctx|arel] @ BcatT^T + bo + x), B direct from BcatT (L2-hot)
    f32x4 yacc = {};
    const short* bcb = BcatT + (size_t)(w * 16 + l15) * 320;
#pragma unroll
    for (int ch = 0; ch < 3; ++ch) {
        const int nkk = (ch == 2) ? 2 : 4;
#pragma unroll
        for (int kk = 0; kk < 4; ++kk) {
            if (kk >= nkk) break;
            bf16x8 a = *(const bf16x8*)&CtxA[l15 * 344 + ch * 128 + kk * 32 + quad * 8];
            bf16x8 b = *(const bf16x8*)(bcb + ch * 128 + kk * 32 + quad * 8);
            yacc = __builtin_amdgcn_mfma_f32_16x16x32_bf16(a, b, yacc, 0, 0, 0);
        }
    }

    // ---- residual + LayerNorm epilogue
    const int col = w * 16 + l15;
    const float bov = bo[col], gv = gamma[col], bev = beta[col];
    float vv[4];
#pragma unroll
    for (int r = 0; r < 4; ++r) {
        int lr = quad * 4 + r;
        vv[r] = yacc[r] + bov + X[(grow0 + lr) * 128 + col];
    }
#pragma unroll
    for (int r = 0; r < 4; ++r) {
        float s = vv[r];
#pragma unroll
        for (int msk = 1; msk < 16; msk <<= 1) s += __shfl_xor(s, msk);
        if (l15 == 0) redM[(quad * 4 + r) * 8 + w] = s;
    }
    __syncthreads();
    float mu[4];
#pragma unroll
    for (int r = 0; r < 4; ++r) {
        int lr = quad * 4 + r;
        float s = 0.f;
#pragma unroll
        for (int j = 0; j < 8; ++j) s += redM[lr * 8 + j];
        mu[r] = s * (1.f / 128.f);
    }
#pragma unroll
    for (int r = 0; r < 4; ++r) {
        float d = vv[r] - mu[r];
        float s = d * d;
#pragma unroll
        for (int msk = 1; msk < 16; msk <<= 1) s += __shfl_xor(s, msk);
        if (l15 == 0) redS[(quad * 4 + r) * 8 + w] = s;
    }
    __syncthreads();
#pragma unroll
    for (int r = 0; r < 4; ++r) {
        int lr = quad * 4 + r;
        float s = 0.f;
#pragma unroll
        for (int j = 0; j < 8; ++j) s += redS[lr * 8 + j];
        float inv = rsqrtf(s * (1.f / 128.f) + 1e-5f);
        float yv = (vv[r] - mu[r]) * inv * gv + bev;
        __builtin_nontemporal_store(yv, &y_g[(grow0 + lr) * 128 + col]);
    }
}

extern "C" void kernel_launch(void* const* d_in, const int* in_sizes, int n_in,
                              void* d_out, int out_size, void* d_ws, size_t ws_size,
                              hipStream_t stream) {
    const float* x     = (const float*)d_in[0];
    const float* Wq    = (const float*)d_in[1];
    const float* bq    = (const float*)d_in[2];
    const float* Wk    = (const float*)d_in[3];
    const float* bk    = (const float*)d_in[4];
    const float* Wv    = (const float*)d_in[5];
    const float* bv    = (const float*)d_in[6];
    const float* rel_k = (const float*)d_in[7];
    const float* rel_v = (const float*)d_in[8];
    const float* Wo    = (const float*)d_in[9];
    const float* bo    = (const float*)d_in[10];
    const float* gamma = (const float*)d_in[11];
    const float* beta  = (const float*)d_in[12];

    char* ws = (char*)d_ws;
    short* kh     = (short*)(ws + 0);          // 8x1024x128 bf16 (2 MB)
    short* vT     = (short*)(ws + 2097152);    // 8x128x1024 bf16 (2 MB)
    short* qcat   = (short*)(ws + 4194304);    // 8192x256 bf16 hi|lo (4 MB)
    short* relcat = (short*)(ws + 8388608);    // 129x384 bf16 in a padded 128 KB slot
    short* BcatT  = (short*)(ws + 8519680);    // 128x320 bf16 (80 KB + pad)
    short* wtab   = (short*)(ws + 8650752);    // 3 sels x (hi|lo) x 128x128 bf16 (192 KB)

    float* y_out = (float*)d_out;
    float* attn  = (float*)d_out + YEL;        // 8x1024x1024 f32

    build_tables<<<dim3(Rn + 107 + 128), 384, 0, stream>>>(
        rel_k, rel_v, Wo, Wq, Wk, Wv, relcat, BcatT, wtab);
    proj<<<dim3(128, 3), 256, 0, stream>>>(x, wtab, bq, bk, bv, qcat, kh, vT);

    fused_attn<<<dim3(64, 1, Bn), 512, 0, stream>>>(
        qcat, kh, vT, relcat, BcatT, x, bo, gamma, beta, attn, y_out);
}

// Round 10
// 153.656 us; speedup vs baseline: 1.0932x; 1.0138x over previous
//
#include <hip/hip_runtime.h>

// B=8, S=1024, H=128, rel rows R=129. All inputs/outputs are float32.
constexpr int Bn = 8, Sn = 1024, Hn = 128, Rn = 129;
constexpr float INV_SCALE = 0.088388347648318447f; // 1/sqrt(128)
constexpr size_t YEL = (size_t)Bn * Sn * Hn;       // y output elements

typedef short bf16x8 __attribute__((ext_vector_type(8)));
typedef short v4s __attribute__((ext_vector_type(4)));
typedef float f32x4 __attribute__((ext_vector_type(4)));
typedef int v4i __attribute__((ext_vector_type(4)));

__device__ __forceinline__ float bf2f(short s) {
    unsigned u = ((unsigned)(unsigned short)s) << 16;
    float f; __builtin_memcpy(&f, &u, 4); return f;
}
__device__ __forceinline__ short f2bf(float f) {
    unsigned u; __builtin_memcpy(&u, &f, 4);
    unsigned r = (u + 0x7fffu + ((u >> 16) & 1u)) >> 16;
    return (short)(r & 0xffffu);
}

// Async 16B global -> LDS (direct-to-LDS DMA; dest = wave-uniform base + lane*16).
__device__ __forceinline__ void gll16(const short* g, short* l) {
    __builtin_amdgcn_global_load_lds(
        (const __attribute__((address_space(1))) void*)g,
        (__attribute__((address_space(3))) void*)l, 16, 0, 0);
}

// Merged table builder:
//   blocks [0, Rn):            relcat[p] = [rh(128) | rh(128) | rl(128)]
//   blocks [Rn, Rn+107):       BcatT[n][k] (ld 320)
//   blocks [Rn+107, Rn+235):   wtab: transposed hi/lo bf16 weights for proj
__global__ __launch_bounds__(384) void build_tables(
    const float* __restrict__ rel_k, const float* __restrict__ rel_v,
    const float* __restrict__ Wo,
    const float* __restrict__ Wq, const float* __restrict__ Wk,
    const float* __restrict__ Wv,
    short* __restrict__ relcat, short* __restrict__ BcatT,
    short* __restrict__ wtab)
{
    if (blockIdx.x < Rn) {
        const int p = blockIdx.x, c = threadIdx.x;
        const int j = (c < 256) ? (c & 127) : (c - 256);
        float v = rel_k[p * Hn + j];
        short h = f2bf(v);
        relcat[p * 384 + c] = (c < 256) ? h : f2bf(v - bf2f(h));
    } else if (blockIdx.x < Rn + 107) {
        int idx = (blockIdx.x - Rn) * 384 + threadIdx.x;   // 0..40959 (320x128)
        if (idx < 320 * 128) {
            int k = idx >> 7, n = idx & 127;
            float v;
            if (k < 128) v = Wo[k * Hn + n];
            else if (k < 257) {
                int p = k - 128; float a = 0.f;
                for (int h = 0; h < Hn; ++h) a += rel_v[p * Hn + h] * Wo[h * Hn + n];
                v = a;
            } else v = 0.f;
            BcatT[n * 320 + k] = f2bf(v);
        }
    } else {
        int idx = (blockIdx.x - Rn - 107) * 384 + threadIdx.x;
        int sel = idx >> 14, rem = idx & 16383;
        int n = rem >> 7, k = rem & 127;
        const float* W = (sel == 0) ? Wq : (sel == 1) ? Wk : Wv;
        float v = W[k * Hn + n];
        short h = f2bf(v);
        wtab[sel * 32768 + n * 128 + k] = h;
        wtab[sel * 32768 + 16384 + n * 128 + k] = f2bf(v - bf2f(h));
    }
}

// MFMA projections: q = xh@wh + xh@wl + xl@wh (xl@wl dropped, ~1.5e-4).
__global__ __launch_bounds__(256) void proj(
    const float* __restrict__ X, const short* __restrict__ wtab,
    const float* __restrict__ bq, const float* __restrict__ bk,
    const float* __restrict__ bv,
    short* __restrict__ qcat, short* __restrict__ kh, short* __restrict__ vT)
{
    __shared__ float xs[64][128];
    const int tid = threadIdx.x;
    const int sel = blockIdx.y;
    const int row0 = blockIdx.x * 64;
    const float* bias = (sel == 0) ? bq : (sel == 1) ? bk : bv;
    const short* wh = wtab + sel * 32768;
    const short* wl = wh + 16384;

#pragma unroll
    for (int it = 0; it < 8; ++it) {
        int u = tid + it * 256;
        int r = u >> 5, c4 = (u & 31) * 4;
        *(float4*)&xs[r][c4] = *(const float4*)(X + (size_t)(row0 + r) * 128 + c4);
    }
    __syncthreads();

    const int w = tid >> 6, lane = tid & 63;
    const int quad = lane >> 4, l15 = lane & 15;

    bf16x8 xh[4], xl[4];
#pragma unroll
    for (int kk = 0; kk < 4; ++kk) {
#pragma unroll
        for (int j = 0; j < 8; ++j) {
            float v = xs[w * 16 + l15][kk * 32 + quad * 8 + j];
            short h = f2bf(v);
            xh[kk][j] = h;
            xl[kk][j] = f2bf(v - bf2f(h));
        }
    }

    f32x4 acc[8] = {};
#pragma unroll
    for (int nt = 0; nt < 8; ++nt) {
        const short* bh = wh + (size_t)(nt * 16 + l15) * 128;
        const short* bl = wl + (size_t)(nt * 16 + l15) * 128;
#pragma unroll
        for (int kk = 0; kk < 4; ++kk) {
            bf16x8 bhf = *(const bf16x8*)(bh + kk * 32 + quad * 8);
            bf16x8 blf = *(const bf16x8*)(bl + kk * 32 + quad * 8);
            acc[nt] = __builtin_amdgcn_mfma_f32_16x16x32_bf16(xh[kk], bhf, acc[nt], 0, 0, 0);
            acc[nt] = __builtin_amdgcn_mfma_f32_16x16x32_bf16(xh[kk], blf, acc[nt], 0, 0, 0);
            acc[nt] = __builtin_amdgcn_mfma_f32_16x16x32_bf16(xl[kk], bhf, acc[nt], 0, 0, 0);
        }
    }

#pragma unroll
    for (int nt = 0; nt < 8; ++nt) {
        int col = nt * 16 + l15;
        float bv2 = bias[col];
#pragma unroll
        for (int r = 0; r < 4; ++r) {
            int row = row0 + w * 16 + quad * 4 + r;
            float v = acc[nt][r] + bv2;
            short h = f2bf(v);
            if (sel == 0) {
                qcat[(size_t)row * 256 + col] = h;
                qcat[(size_t)row * 256 + 128 + col] = f2bf(v - bf2f(h));
            } else if (sel == 1) {
                kh[(size_t)row * 128 + col] = h;
            } else {
                int b = row >> 10, i = row & (Sn - 1);
                vT[(size_t)b * 131072 + (size_t)col * 1024 + i] = h;
            }
        }
    }
}

// Fully fused: qrel (merged) + scores + softmax + attn-write + P@V +
// [ctx|arel]@BcatT + residual + LayerNorm -> y.
// Verified-best structure (r7/r8): block-wide async gll16 double-buffered
// staging with __syncthreads per round. The counted-vmcnt wave-async variant
// (r9) raced (absmax 2.09) for reasons not located analytically — reverted.
__global__ __launch_bounds__(512, 4) void fused_attn(
    const short* __restrict__ qcat, const short* __restrict__ kh,
    const short* __restrict__ vT, const short* __restrict__ relcat,
    const short* __restrict__ BcatT,
    const float* __restrict__ X, const float* __restrict__ bo,
    const float* __restrict__ gamma, const float* __restrict__ beta,
    float* __restrict__ attn_g, float* __restrict__ y_g)
{
    __shared__ __align__(16) char smem[78848];
    short* bufS = (short*)smem;               // 32,768 B: 2 x 16,384 halves
    short* Pb   = (short*)(smem + 32768);     // [16][1032] bf16 P      (33,024 B)
    short* CtxA = (short*)(smem + 65792);     // [16][344]  [ctx|arel]  (11,008 B)
    float* QrL  = (float*)(smem + 65792);     // [16][132] overlays CtxA (dead before it)
    float* redM = (float*)(smem + 76800);     // 4x [16][8] reduction arrays
    float* redS = redM + 128;
    float* redL = redS + 128;
    float* redH = redL + 128;

    const int tid = threadIdx.x;
    const int w = tid >> 6, lane = tid & 63;
    const int quad = lane >> 4, l15 = lane & 15;
    // XCD batch-affinity swizzle (bijective: 512 % 8 == 0).
    const int lb = blockIdx.x + (blockIdx.z << 6);   // 0..511
    const int bz = lb & 7;
    const int row0 = (lb >> 3) << 4;
    const size_t grow0 = (size_t)bz * Sn + row0;

    const short* khb  = kh + (size_t)bz * Sn * 128;
    const short* vtb0 = vT + (size_t)bz * 131072;

    auto stage_kh = [&](int kt2) {
        const short* base = khb + (size_t)((kt2 >> 1) * 128) * 128 + (kt2 & 1) * 64;
        short* dst = bufS + (kt2 & 1) * 8192;
#pragma unroll
        for (int it = 0; it < 2; ++it) {
            int g = tid + it * 512;
            int r = g >> 3, c = g & 7;
            gll16(base + r * 128 + ((c ^ (r & 7)) * 8), dst + g * 8);
        }
    };
    auto stage_v = [&](int kc2) {
        const short* base = vtb0 + (kc2 >> 1) * 128 + (kc2 & 1) * 64;
        short* dst = bufS + (kc2 & 1) * 8192;
#pragma unroll
        for (int it = 0; it < 2; ++it) {
            int g = tid + it * 512;
            int r = g >> 3, c = g & 7;
            gll16(base + r * 1024 + ((c ^ (r & 7)) * 8), dst + g * 8);
        }
    };

    // issue first kh half-tile now; the qrel prologue below hides its latency
    stage_kh(0);

    // A-frags: q strip rows from qcat hi half (one-time per-lane loads)
    bf16x8 afr[4];
#pragma unroll
    for (int kk = 0; kk < 4; ++kk)
        afr[kk] = *(const bf16x8*)(qcat + (grow0 + l15) * 256 + kk * 32 + quad * 8);

    // ---- merged qrel prologue: QrL[lr][p] = q_f32(lr) . rel_k(p)
    {
        const short* aq = qcat + (grow0 + l15) * 256;
        const short* br = relcat + (size_t)(w * 16 + l15) * 384;
        const short* br2 = relcat + (size_t)(128 + l15) * 384;  // wave 0 extra tile
        f32x4 qacc = {};
        f32x4 qacc2 = {};
#pragma unroll
        for (int ks = 0; ks < 12; ++ks) {
            int koff = ks * 32 + quad * 8;
            int srcc = (koff >= 256) ? koff - 256 : koff;
            bf16x8 qa = *(const bf16x8*)(aq + srcc);
            bf16x8 qb = *(const bf16x8*)(br + ks * 32 + quad * 8);
            qacc = __builtin_amdgcn_mfma_f32_16x16x32_bf16(qa, qb, qacc, 0, 0, 0);
            if (w == 0) {
                bf16x8 qb2 = *(const bf16x8*)(br2 + ks * 32 + quad * 8);
                qacc2 = __builtin_amdgcn_mfma_f32_16x16x32_bf16(qa, qb2, qacc2, 0, 0, 0);
            }
        }
#pragma unroll
        for (int r = 0; r < 4; ++r)
            QrL[(quad * 4 + r) * 132 + w * 16 + l15] = qacc[r];
        if (w == 0 && l15 == 0) {
#pragma unroll
            for (int r = 0; r < 4; ++r)
                QrL[(quad * 4 + r) * 132 + 128] = qacc2[r];
        }
    }
    __syncthreads();   // QrL complete; stage_kh(0) drained

    // ---- phase 1: scores, 16 dbuf'd half-tile rounds
    f32x4 acc[8] = {};
#pragma unroll
    for (int kt2 = 0; kt2 < 16; ++kt2) {
        if (kt2 < 15) stage_kh(kt2 + 1);     // issue BEFORE compute (T3-min)
        const short* hb = bufS + (kt2 & 1) * 8192;
        const int rb = w * 16 + l15;
#pragma unroll
        for (int kk = 0; kk < 2; ++kk) {
            int j = (kk * 4 + quad) ^ (l15 & 7);
            bf16x8 b = *(const bf16x8*)(hb + rb * 64 + j * 8);
            acc[kt2 >> 1] = __builtin_amdgcn_mfma_f32_16x16x32_bf16(
                afr[(kt2 & 1) * 2 + kk], b, acc[kt2 >> 1], 0, 0, 0);
        }
        __syncthreads();   // drains stage(kt2+1); protects next overwrite
    }

    // issue first vT half now — drained by softmax's own barriers
    stage_v(0);

    // ---- scale + qrel + row-max
    float mx[4];
#pragma unroll
    for (int r = 0; r < 4; ++r) {
        int lr = quad * 4 + r, i = row0 + lr;
        float m = -3.4e38f;
#pragma unroll
        for (int kt = 0; kt < 8; ++kt) {
            int col = kt * 128 + w * 16 + l15;
            int d = col - i; d = (d < -64) ? -64 : (d > 64 ? 64 : d);
            float v = acc[kt][r] * INV_SCALE + QrL[lr * 132 + d + 64];
            acc[kt][r] = v;
            m = fmaxf(m, v);
        }
#pragma unroll
        for (int msk = 1; msk < 16; msk <<= 1) m = fmaxf(m, __shfl_xor(m, msk));
        if (l15 == 0) redM[lr * 8 + w] = m;
    }
    __syncthreads();
#pragma unroll
    for (int r = 0; r < 4; ++r) {
        int lr = quad * 4 + r;
        float m = redM[lr * 8];
#pragma unroll
        for (int j = 1; j < 8; ++j) m = fmaxf(m, redM[lr * 8 + j]);
        mx[r] = m;
    }

    // ---- exp + partial sums (s, lo, hi)
#pragma unroll
    for (int r = 0; r < 4; ++r) {
        int lr = quad * 4 + r, i = row0 + lr;
        float s = 0.f, lo = 0.f, hi = 0.f;
#pragma unroll
        for (int kt = 0; kt < 8; ++kt) {
            float e = __expf(acc[kt][r] - mx[r]);
            acc[kt][r] = e;
            s += e;
            int col = kt * 128 + w * 16 + l15;
            lo += (col <= i - 64) ? e : 0.f;
            hi += (col >= i + 64) ? e : 0.f;
        }
#pragma unroll
        for (int msk = 1; msk < 16; msk <<= 1) {
            s += __shfl_xor(s, msk);
            lo += __shfl_xor(lo, msk);
            hi += __shfl_xor(hi, msk);
        }
        if (l15 == 0) { redS[lr * 8 + w] = s; redL[lr * 8 + w] = lo; redH[lr * 8 + w] = hi; }
    }
    __syncthreads();

    // ---- normalize into Pb (bf16)
#pragma unroll
    for (int r = 0; r < 4; ++r) {
        int lr = quad * 4 + r;
        float s = 0.f;
#pragma unroll
        for (int j = 0; j < 8; ++j) s += redS[lr * 8 + j];
        float inv = 1.0f / s;
#pragma unroll
        for (int kt = 0; kt < 8; ++kt) {
            int col = kt * 128 + w * 16 + l15;
            Pb[lr * 1032 + col] = f2bf(acc[kt][r] * inv);
        }
    }
    __syncthreads();   // Pb complete; stage_v(0) also drained by now

    // ---- attn f32 output: coalesced NON-TEMPORAL f32x4 stores from Pb
    {
        float* ab = attn_g + grow0 * Sn;
#pragma unroll
        for (int it = 0; it < 8; ++it) {
            int u = tid + it * 512;            // 16 rows x 256 float4
            int r = u >> 8, c4 = (u & 255) * 4;
            v4s pv = *(const v4s*)&Pb[r * 1032 + c4];
            f32x4 o;
            o[0] = bf2f(pv[0]); o[1] = bf2f(pv[1]);
            o[2] = bf2f(pv[2]); o[3] = bf2f(pv[3]);
            __builtin_nontemporal_store(o, (f32x4*)(ab + (size_t)r * Sn + c4));
        }
    }

    // ---- phase 3: ctx = P @ V, 16 dbuf'd vT half-tile rounds
    f32x4 cacc = {};
#pragma unroll
    for (int kc2 = 0; kc2 < 16; ++kc2) {
        if (kc2 < 15) stage_v(kc2 + 1);
        const short* hb = bufS + (kc2 & 1) * 8192;
        const int rb = w * 16 + l15;
#pragma unroll
        for (int kk = 0; kk < 2; ++kk) {
            bf16x8 a = *(const bf16x8*)&Pb[l15 * 1032 + kc2 * 64 + kk * 32 + quad * 8];
            int j = (kk * 4 + quad) ^ (l15 & 7);
            bf16x8 b = *(const bf16x8*)(hb + rb * 64 + j * 8);
            cacc = __builtin_amdgcn_mfma_f32_16x16x32_bf16(a, b, cacc, 0, 0, 0);
        }
        __syncthreads();
    }

    // ---- build CtxA = [bf16(ctx) | arel(129) | 0] in LDS (overlays dead QrL)
#pragma unroll
    for (int r = 0; r < 4; ++r)
        CtxA[(quad * 4 + r) * 344 + w * 16 + l15] = f2bf(cacc[r]);
#pragma unroll
    for (int rr = 0; rr < 2; ++rr) {
        int lr = w * 2 + rr, i = row0 + lr;
        float s = 0.f, lo = 0.f, hi = 0.f;
#pragma unroll
        for (int j = 0; j < 8; ++j) {
            s += redS[lr * 8 + j]; lo += redL[lr * 8 + j]; hi += redH[lr * 8 + j];
        }
        float inv = 1.0f / s;
        float v0;
        if (lane == 0) v0 = lo * inv;
        else { int c = i + lane - 64; v0 = (c >= 0 && c < Sn) ? bf2f(Pb[lr * 1032 + c]) : 0.f; }
        CtxA[lr * 344 + 128 + lane] = f2bf(v0);
        int c1 = i + lane;
        CtxA[lr * 344 + 192 + lane] = (c1 < Sn) ? Pb[lr * 1032 + c1] : (short)0;
        CtxA[lr * 344 + 256 + lane] = (lane == 0) ? f2bf(hi * inv) : (short)0;
    }
    __syncthreads();

    // ---- phase 4: y = LN([ctx|arel] @ BcatT^T + bo + x), B direct from BcatT (L2-hot)
    f32x4 yacc = {};
    const short* bcb = BcatT + (size_t)(w * 16 + l15) * 320;
#pragma unroll
    for (int ch = 0; ch < 3; ++ch) {
        const int nkk = (ch == 2) ? 2 : 4;
#pragma unroll
        for (int kk = 0; kk < 4; ++kk) {
            if (kk >= nkk) break;
            bf16x8 a = *(const bf16x8*)&CtxA[l15 * 344 + ch * 128 + kk * 32 + quad * 8];
            bf16x8 b = *(const bf16x8*)(bcb + ch * 128 + kk * 32 + quad * 8);
            yacc = __builtin_amdgcn_mfma_f32_16x16x32_bf16(a, b, yacc, 0, 0, 0);
        }
    }

    // ---- residual + LayerNorm epilogue
    const int col = w * 16 + l15;
    const float bov = bo[col], gv = gamma[col], bev = beta[col];
    float vv[4];
#pragma unroll
    for (int r = 0; r < 4; ++r) {
        int lr = quad * 4 + r;
        vv[r] = yacc[r] + bov + X[(grow0 + lr) * 128 + col];
    }
#pragma unroll
    for (int r = 0; r < 4; ++r) {
        float s = vv[r];
#pragma unroll
        for (int msk = 1; msk < 16; msk <<= 1) s += __shfl_xor(s, msk);
        if (l15 == 0) redM[(quad * 4 + r) * 8 + w] = s;
    }
    __syncthreads();
    float mu[4];
#pragma unroll
    for (int r = 0; r < 4; ++r) {
        int lr = quad * 4 + r;
        float s = 0.f;
#pragma unroll
        for (int j = 0; j < 8; ++j) s += redM[lr * 8 + j];
        mu[r] = s * (1.f / 128.f);
    }
#pragma unroll
    for (int r = 0; r < 4; ++r) {
        float d = vv[r] - mu[r];
        float s = d * d;
#pragma unroll
        for (int msk = 1; msk < 16; msk <<= 1) s += __shfl_xor(s, msk);
        if (l15 == 0) redS[(quad * 4 + r) * 8 + w] = s;
    }
    __syncthreads();
#pragma unroll
    for (int r = 0; r < 4; ++r) {
        int lr = quad * 4 + r;
        float s = 0.f;
#pragma unroll
        for (int j = 0; j < 8; ++j) s += redS[lr * 8 + j];
        float inv = rsqrtf(s * (1.f / 128.f) + 1e-5f);
        float yv = (vv[r] - mu[r]) * inv * gv + bev;
        __builtin_nontemporal_store(yv, &y_g[(grow0 + lr) * 128 + col]);
    }
}

extern "C" void kernel_launch(void* const* d_in, const int* in_sizes, int n_in,
                              void* d_out, int out_size, void* d_ws, size_t ws_size,
                              hipStream_t stream) {
    const float* x     = (const float*)d_in[0];
    const float* Wq    = (const float*)d_in[1];
    const float* bq    = (const float*)d_in[2];
    const float* Wk    = (const float*)d_in[3];
    const float* bk    = (const float*)d_in[4];
    const float* Wv    = (const float*)d_in[5];
    const float* bv    = (const float*)d_in[6];
    const float* rel_k = (const float*)d_in[7];
    const float* rel_v = (const float*)d_in[8];
    const float* Wo    = (const float*)d_in[9];
    const float* bo    = (const float*)d_in[10];
    const float* gamma = (const float*)d_in[11];
    const float* beta  = (const float*)d_in[12];

    char* ws = (char*)d_ws;
    short* kh     = (short*)(ws + 0);          // 8x1024x128 bf16 (2 MB)
    short* vT     = (short*)(ws + 2097152);    // 8x128x1024 bf16 (2 MB)
    short* qcat   = (short*)(ws + 4194304);    // 8192x256 bf16 hi|lo (4 MB)
    short* relcat = (short*)(ws + 8388608);    // 129x384 bf16 in a padded 128 KB slot
    short* BcatT  = (short*)(ws + 8519680);    // 128x320 bf16 (80 KB + pad)
    short* wtab   = (short*)(ws + 8650752);    // 3 sels x (hi|lo) x 128x128 bf16 (192 KB)

    float* y_out = (float*)d_out;
    float* attn  = (float*)d_out + YEL;        // 8x1024x1024 f32

    build_tables<<<dim3(Rn + 107 + 128), 384, 0, stream>>>(
        rel_k, rel_v, Wo, Wq, Wk, Wv, relcat, BcatT, wtab);
    proj<<<dim3(128, 3), 256, 0, stream>>>(x, wtab, bq, bk, bv, qcat, kh, vT);

    fused_attn<<<dim3(64, 1, Bn), 512, 0, stream>>>(
        qcat, kh, vT, relcat, BcatT, x, bo, gamma, beta, attn, y_out);
}